// Round 8
// baseline (318.840 us; speedup 1.0000x reference)
//
#include <hip/hip_runtime.h>
#include <hip/hip_bf16.h>

typedef unsigned short ushort_t;
typedef __attribute__((ext_vector_type(4))) float floatx4;
typedef __attribute__((ext_vector_type(8))) short short8;

__device__ __forceinline__ float bf2f(ushort_t u) {
    union { unsigned int i; float f; } v; v.i = ((unsigned int)u) << 16; return v.f;
}
__device__ __forceinline__ ushort_t f2bf(float f) {
    union { float f; unsigned int i; } v; v.f = f;
    unsigned int i = v.i;
    i += 0x7fffu + ((i >> 16) & 1u);            // RNE
    return (ushort_t)(i >> 16);
}
__device__ __forceinline__ float fsig(float x)  { return 1.f / (1.f + __expf(-x)); }
__device__ __forceinline__ float ftanh(float x) { return 1.f - 2.f / (__expf(2.f * x) + 1.f); }

__device__ __forceinline__ floatx4 MFMA16(short8 a, short8 b, floatx4 c) {
    return __builtin_amdgcn_mfma_f32_16x16x32_bf16(a, b, c, 0, 0, 0);
}

// LDS-only barrier: waits LDS ops, NOT vmem (stores/prefetch stay in flight).
__device__ __forceinline__ void bar_lds() {
    asm volatile("s_waitcnt lgkmcnt(0)" ::: "memory");
    __builtin_amdgcn_s_barrier();
}

// Swizzled LDS index for [chunk c][seq m][8 elems] bf16 tiles.
#define XIDX(c, m) ((((c) * 16) + ((m) ^ ((c) & 15))) * 8)

// ---------------------------------------------------------------------------
// K1: lengths + dtype detect. Blocks 0..31: per-doc lens + dmax (race-free).
// Block 32: dtype detection on raw emb words.
// ---------------------------------------------------------------------------
__global__ __launch_bounds__(64) void lens_kernel(const int* __restrict__ x,
                                                  const unsigned int* __restrict__ raw,
                                                  int* wlens, int* slens, int* dmax,
                                                  int* flag) {
    int b = blockIdx.x, s = threadIdx.x;
    if (b == 32) {
        int c = 0;
        for (int i = 0; i < 16; ++i) {
            unsigned int v = raw[s * 16 + i];
            unsigned int e = (v >> 7) & 0xFFu;   // low-ushort bf16 exponent field
            if (e > 0x7Bu) ++c;
        }
        c += __shfl_xor(c, 1);  c += __shfl_xor(c, 2);  c += __shfl_xor(c, 4);
        c += __shfl_xor(c, 8);  c += __shfl_xor(c, 16); c += __shfl_xor(c, 32);
        if (s == 0) *flag = (c > 64) ? 1 : 0;    // 1 => inputs are f32
        return;
    }
    int last = 0;
    if (s < 32) {
        const int* tok = x + (b * 32 + s) * 64;
        for (int t = 0; t < 64; t += 4) {
            int4 v = *(const int4*)(tok + t);
            if (v.x) last = t + 1;
            if (v.y) last = t + 2;
            if (v.z) last = t + 3;
            if (v.w) last = t + 4;
        }
        wlens[b * 32 + s] = last ? last : 1;
    }
    int len = (s < 32) ? (last ? last : 1) : 0;
    int lm = len;
    for (int off = 32; off; off >>= 1) lm = max(lm, __shfl_xor(lm, off));
    unsigned long long mask = __ballot(s < 32 && last > 0);
    if (s == 0) {
        slens[b] = mask ? (63 - (int)__clzll(mask) + 1) : 1;
        dmax[b] = lm;
    }
}

// ---------------------------------------------------------------------------
// K0b: canonicalize all float inputs to bf16 in ws.
// ---------------------------------------------------------------------------
struct ConvArgs {
    const void* src[25];
    int dstoff[25];
    int count[25];
    int cumblk[26];
};

__global__ __launch_bounds__(256) void convert_kernel(ConvArgs a, ushort_t* __restrict__ dst,
                                                      const int* __restrict__ flag) {
    int b = blockIdx.x;
    int lo = 0, hi = 24;
    while (lo < hi) { int mid = (lo + hi + 1) >> 1; if (a.cumblk[mid] <= b) lo = mid; else hi = mid - 1; }
    int j = lo;
    size_t base = (size_t)(b - a.cumblk[j]) * 2048 + (size_t)threadIdx.x * 8;
    if (base >= (size_t)a.count[j]) return;
    ushort_t* out = dst + a.dstoff[j] + base;
    if (*flag) {
        const float* s = (const float*)a.src[j] + base;
        float4 v0 = *(const float4*)s;
        float4 v1 = *(const float4*)(s + 4);
        union { ushort_t u[8]; uint4 v; } o;
        o.u[0] = f2bf(v0.x); o.u[1] = f2bf(v0.y); o.u[2] = f2bf(v0.z); o.u[3] = f2bf(v0.w);
        o.u[4] = f2bf(v1.x); o.u[5] = f2bf(v1.y); o.u[6] = f2bf(v1.z); o.u[7] = f2bf(v1.w);
        *(uint4*)out = o.v;
    } else {
        *(uint4*)out = *(const uint4*)((const ushort_t*)a.src[j] + base);
    }
}

// ---------------------------------------------------------------------------
// Word-level BiGRU v3: fused gather+proj+recurrence, in-register gates.
// grid (64, 2); 512 thr. x B-fragments loaded DIRECTLY from emb into registers
// (no LDS x staging -> no vmcnt store-coupling before the barrier). h is the
// only LDS exchange (double-buffered, bar_lds per step).
// ---------------------------------------------------------------------------
__global__ __launch_bounds__(512, 2) void word_gru_kernel(
        const int* __restrict__ x, const ushort_t* __restrict__ emb,
        const ushort_t* __restrict__ Wih_f, const ushort_t* __restrict__ Whh_f,
        const ushort_t* __restrict__ bih_f, const ushort_t* __restrict__ bhh_f,
        const ushort_t* __restrict__ Wih_b, const ushort_t* __restrict__ Whh_b,
        const ushort_t* __restrict__ bih_b, const ushort_t* __restrict__ bhh_b,
        const int* __restrict__ lens, ushort_t* __restrict__ out) {
    const int T = 64;
    __shared__ ushort_t h_buf[2][2048];      // swizzled [k/8][m(16)][8] bf16
    __shared__ float bsum_lds[256];
    __shared__ float bihn_lds[128];
    __shared__ float bhhn_lds[128];
    __shared__ int tok_lds[1024];            // TRANSPOSED [t][s] (bank-friendly)

    int tid = threadIdx.x;
    int d = blockIdx.y;
    int n0 = blockIdx.x * 16;
    const ushort_t* Wih = d ? Wih_b : Wih_f;
    const ushort_t* Whh = d ? Whh_b : Whh_f;
    const ushort_t* bih = d ? bih_b : bih_f;
    const ushort_t* bhh = d ? bhh_b : bhh_f;
    int lane = tid & 63, wave = tid >> 6;
    int l15 = lane & 15, l4 = (lane >> 4) & 3;
    int jt = wave * 16;
    int j0 = jt + l4 * 4;

    for (int i = tid; i < 1024; i += 512) {
        int t = i >> 4, s = i & 15;
        tok_lds[i] = x[(n0 + s) * 64 + t];
    }
    if (tid < 256) bsum_lds[tid] = bf2f(bih[tid]) + bf2f(bhh[tid]);
    else if (tid < 384) {
        bihn_lds[tid - 256] = bf2f(bih[tid]);
        bhhn_lds[tid - 256] = bf2f(bhh[tid]);
    }
    { uint2 z = {0u, 0u}; *(uint2*)&h_buf[0][tid * 4] = z; }

    short8 wr[4], wz[4], wn[4], ur[4], uz[4], un[4];
    #pragma unroll
    for (int kf = 0; kf < 4; ++kf) {
        int col = kf * 32 + l4 * 8;
        wr[kf] = *(const short8*)(Wih + (size_t)(jt + l15) * 128 + col);
        wz[kf] = *(const short8*)(Wih + (size_t)(128 + jt + l15) * 128 + col);
        wn[kf] = *(const short8*)(Wih + (size_t)(256 + jt + l15) * 128 + col);
        ur[kf] = *(const short8*)(Whh + (size_t)(jt + l15) * 128 + col);
        uz[kf] = *(const short8*)(Whh + (size_t)(128 + jt + l15) * 128 + col);
        un[kf] = *(const short8*)(Whh + (size_t)(256 + jt + l15) * 128 + col);
    }
    __syncthreads();                         // tok_lds + biases + h zero ready

    floatx4 br  = *(floatx4*)&bsum_lds[j0];
    floatx4 bz  = *(floatx4*)&bsum_lds[128 + j0];
    floatx4 bxn = *(floatx4*)&bihn_lds[j0];
    floatx4 bhn = *(floatx4*)&bhhn_lds[j0];
    int lv = lens[n0 + l15];
    float hreg[4] = {0.f, 0.f, 0.f, 0.f};

    // x B-fragment for this lane: emb[tok[l15][t]][kf*32 + l4*8 .. +7]
    short8 xc[4], xn_[4];
    {
        int t0 = d ? (T - 1) : 0;
        size_t rb = (size_t)tok_lds[t0 * 16 + l15] * 128 + l4 * 8;
        #pragma unroll
        for (int kf = 0; kf < 4; ++kf)
            xc[kf] = *(const short8*)(emb + rb + kf * 32);
    }

    for (int ti = 0; ti < T; ++ti) {
        int t = d ? (T - 1 - ti) : ti;
        bool have_next = (ti + 1) < T;
        if (have_next) {                     // issue next x-frag loads early
            int tn = d ? (T - 2 - ti) : (ti + 1);
            size_t rb = (size_t)tok_lds[tn * 16 + l15] * 128 + l4 * 8;
            #pragma unroll
            for (int kf = 0; kf < 4; ++kf)
                xn_[kf] = *(const short8*)(emb + rb + kf * 32);
        }
        short8 hb[4];
        #pragma unroll
        for (int kf = 0; kf < 4; ++kf)
            hb[kf] = *(const short8*)&h_buf[ti & 1][XIDX(kf * 4 + l4, l15)];
        floatx4 arx = br, azx = bz, axn = bxn;
        floatx4 arh = {0.f, 0.f, 0.f, 0.f}, azh = {0.f, 0.f, 0.f, 0.f}, ahn = bhn;
        #pragma unroll
        for (int kf = 0; kf < 4; ++kf) {
            arx = MFMA16(wr[kf], xc[kf], arx);
            azx = MFMA16(wz[kf], xc[kf], azx);
            axn = MFMA16(wn[kf], xc[kf], axn);
        }
        #pragma unroll
        for (int kf = 0; kf < 4; ++kf) {
            arh = MFMA16(ur[kf], hb[kf], arh);
            azh = MFMA16(uz[kf], hb[kf], azh);
            ahn = MFMA16(un[kf], hb[kf], ahn);
        }
        bool valid = t < lv;
        ushort_t hu[4], ou[4];
        #pragma unroll
        for (int i = 0; i < 4; ++i) {
            float r  = fsig(arx[i] + arh[i]);
            float z  = fsig(azx[i] + azh[i]);
            float nn = ftanh(axn[i] + r * ahn[i]);
            float hv = valid ? (nn + z * (hreg[i] - nn)) : hreg[i];
            hreg[i] = hv;
            hu[i] = f2bf(hv);
            ou[i] = valid ? hu[i] : (ushort_t)0;
        }
        ushort4 h4; h4.x = hu[0]; h4.y = hu[1]; h4.z = hu[2]; h4.w = hu[3];
        ushort4 o4; o4.x = ou[0]; o4.y = ou[1]; o4.z = ou[2]; o4.w = ou[3];
        *(ushort4*)&h_buf[(ti & 1) ^ 1][XIDX(j0 >> 3, l15) + (j0 & 7)] = h4;
        *(ushort4*)(out + ((size_t)(n0 + l15) * T + t) * 256 + d * 128 + j0) = o4;
        if (have_next) {
            #pragma unroll
            for (int kf = 0; kf < 4; ++kf) xc[kf] = xn_[kf];
        }
        bar_lds();
    }
}

// ---------------------------------------------------------------------------
// Sentence xp GEMM -> transposed layout spT.
// spT element (doc, t, n) stored at [(dblk*32 + t)*96 + (n>>2)]*64 + (doc&15)*4 + (n&3)
// where dblk = doc>>4. grid (16, 12): by<6 fwd n-tiles, by>=6 bwd.
// ---------------------------------------------------------------------------
__global__ __launch_bounds__(256) void spt_gemm_kernel(const ushort_t* __restrict__ A,
                                                       const ushort_t* __restrict__ Bf_,
                                                       const ushort_t* __restrict__ biasf,
                                                       ushort_t* __restrict__ Tf_,
                                                       const ushort_t* __restrict__ Bb_,
                                                       const ushort_t* __restrict__ biasb,
                                                       ushort_t* __restrict__ Tb_) {
    __shared__ ushort_t As[64 * 256];
    __shared__ ushort_t Bs[64 * 256];
    const int K = 256;
    int tid = threadIdx.x;
    int by = blockIdx.y;
    bool sb = by >= 6;
    int n0 = (sb ? by - 6 : by) * 64;
    const ushort_t* B = sb ? Bb_ : Bf_;
    const ushort_t* bias = sb ? biasb : biasf;
    ushort_t* Tp = sb ? Tb_ : Tf_;
    int m0 = blockIdx.x * 64;
    for (int idx = tid; idx < 2048; idx += 256) {
        int m = idx & 63, c = idx >> 6;
        *(uint4*)&As[(c * 64 + m) * 8] = *(const uint4*)(A + (size_t)(m0 + m) * K + c * 8);
    }
    for (int idx = tid; idx < 2048; idx += 256) {
        int n = idx & 63, c = idx >> 6;
        *(uint4*)&Bs[(c * 64 + n) * 8] = *(const uint4*)(B + (size_t)(n0 + n) * K + c * 8);
    }
    __syncthreads();
    int lane = tid & 63, wave = tid >> 6;
    int wm = (wave & 1) * 32, wn = (wave >> 1) * 32;
    int l15 = lane & 15, l4 = lane >> 4;
    floatx4 acc[2][2] = {};
    for (int kf = 0; kf < 8; ++kf) {
        int c = kf * 4 + l4;
        short8 a0 = *(const short8*)&As[(c * 64 + wm + l15) * 8];
        short8 a1 = *(const short8*)&As[(c * 64 + wm + 16 + l15) * 8];
        short8 b0 = *(const short8*)&Bs[(c * 64 + wn + l15) * 8];
        short8 b1 = *(const short8*)&Bs[(c * 64 + wn + 16 + l15) * 8];
        acc[0][0] = MFMA16(a0, b0, acc[0][0]);
        acc[0][1] = MFMA16(a0, b1, acc[0][1]);
        acc[1][0] = MFMA16(a1, b0, acc[1][0]);
        acc[1][1] = MFMA16(a1, b1, acc[1][1]);
    }
    for (int nt = 0; nt < 2; ++nt) {
        int n = n0 + wn + nt * 16 + l15;
        float bv = bf2f(bias[n]);
        int jc = n >> 2, ji = n & 3;
        for (int mt = 0; mt < 2; ++mt) {
            int mbase = m0 + wm + mt * 16 + l4 * 4;
            #pragma unroll
            for (int i = 0; i < 4; ++i) {
                int m = mbase + i;                  // global sent row = doc*32 + t
                int doc = m >> 5, t = m & 31;
                size_t dst = ((size_t)((doc >> 4) * 32 + t) * 96 + jc) * 64
                           + (doc & 15) * 4 + ji;
                Tp[dst] = f2bf(acc[mt][nt][i] + bv);
            }
        }
    }
}

// ---------------------------------------------------------------------------
// Sentence-level BiGRU (lean): h-only MFMAs; xp read from spT with coalesced
// register prefetch (1 step ahead). grid (2, 2); 512 thr; T=32.
// ---------------------------------------------------------------------------
__global__ __launch_bounds__(512, 1) void sent_gru_kernel(
        const ushort_t* __restrict__ spT_f, const ushort_t* __restrict__ spT_b,
        const ushort_t* __restrict__ Whh_f, const ushort_t* __restrict__ Whh_b,
        const ushort_t* __restrict__ bhh_f, const ushort_t* __restrict__ bhh_b,
        const int* __restrict__ lens, ushort_t* __restrict__ out) {
    const int T = 32;
    __shared__ ushort_t h_buf[2][2048];      // swizzled [k/8][m][8]
    __shared__ float bhh_lds[384];

    int tid = threadIdx.x;
    int d = blockIdx.y;
    int n0 = blockIdx.x * 16;
    const ushort_t* spT = d ? spT_b : spT_f;
    const ushort_t* Whh = d ? Whh_b : Whh_f;
    const ushort_t* bhh = d ? bhh_b : bhh_f;
    int lane = tid & 63, wave = tid >> 6;
    int l15 = lane & 15, l4 = (lane >> 4) & 3;
    int jt = wave * 16;
    int j0 = jt + l4 * 4;
    int jc = j0 >> 2;

    if (tid < 384) bhh_lds[tid] = bf2f(bhh[tid]);
    { uint2 z = {0u, 0u}; *(uint2*)&h_buf[0][tid * 4] = z; }

    short8 ur[4], uz[4], un[4];
    #pragma unroll
    for (int kf = 0; kf < 4; ++kf) {
        int col = kf * 32 + l4 * 8;
        ur[kf] = *(const short8*)(Whh + (size_t)(jt + l15) * 128 + col);
        uz[kf] = *(const short8*)(Whh + (size_t)(128 + jt + l15) * 128 + col);
        un[kf] = *(const short8*)(Whh + (size_t)(256 + jt + l15) * 128 + col);
    }
    __syncthreads();

    floatx4 br  = *(floatx4*)&bhh_lds[j0];
    floatx4 bz  = *(floatx4*)&bhh_lds[128 + j0];
    floatx4 bhn = *(floatx4*)&bhh_lds[256 + j0];
    int lv = lens[n0 + l15];
    float hreg[4] = {0.f, 0.f, 0.f, 0.f};

    // spT base for this block: dblk = n0/16
    const ushort_t* sp = spT + (size_t)(blockIdx.x * 32) * 96 * 64 + l15 * 4;
    ushort4 xr_c, xz_c, xn_c, xr_n, xz_n, xn_n;
    {
        int t0 = d ? (T - 1) : 0;
        size_t rb = (size_t)t0 * 96 * 64;
        xr_c = *(const ushort4*)(sp + rb + (size_t)jc * 64);
        xz_c = *(const ushort4*)(sp + rb + (size_t)(32 + jc) * 64);
        xn_c = *(const ushort4*)(sp + rb + (size_t)(64 + jc) * 64);
    }

    for (int ti = 0; ti < T; ++ti) {
        int t = d ? (T - 1 - ti) : ti;
        int cur = ti & 1;
        bool have_next = (ti + 1) < T;
        if (have_next) {
            int tn = d ? (T - 2 - ti) : (ti + 1);
            size_t rb = (size_t)tn * 96 * 64;
            xr_n = *(const ushort4*)(sp + rb + (size_t)jc * 64);
            xz_n = *(const ushort4*)(sp + rb + (size_t)(32 + jc) * 64);
            xn_n = *(const ushort4*)(sp + rb + (size_t)(64 + jc) * 64);
        }
        floatx4 ar = br, az = bz, ahn = bhn;
        #pragma unroll
        for (int kf = 0; kf < 4; ++kf) {
            short8 hb = *(const short8*)&h_buf[cur][XIDX(kf * 4 + l4, l15)];
            ar  = MFMA16(ur[kf], hb, ar);
            az  = MFMA16(uz[kf], hb, az);
            ahn = MFMA16(un[kf], hb, ahn);
        }
        float xr[4] = {bf2f(xr_c.x), bf2f(xr_c.y), bf2f(xr_c.z), bf2f(xr_c.w)};
        float xz[4] = {bf2f(xz_c.x), bf2f(xz_c.y), bf2f(xz_c.z), bf2f(xz_c.w)};
        float xn[4] = {bf2f(xn_c.x), bf2f(xn_c.y), bf2f(xn_c.z), bf2f(xn_c.w)};
        bool valid = t < lv;
        ushort_t hu[4], ou[4];
        #pragma unroll
        for (int i = 0; i < 4; ++i) {
            float r  = fsig(xr[i] + ar[i]);
            float z  = fsig(xz[i] + az[i]);
            float nn = ftanh(xn[i] + r * ahn[i]);
            float hv = valid ? (nn + z * (hreg[i] - nn)) : hreg[i];
            hreg[i] = hv;
            hu[i] = f2bf(hv);
            ou[i] = valid ? hu[i] : (ushort_t)0;
        }
        ushort4 h4; h4.x = hu[0]; h4.y = hu[1]; h4.z = hu[2]; h4.w = hu[3];
        ushort4 o4; o4.x = ou[0]; o4.y = ou[1]; o4.z = ou[2]; o4.w = ou[3];
        *(ushort4*)&h_buf[cur ^ 1][XIDX(j0 >> 3, l15) + (j0 & 7)] = h4;
        *(ushort4*)(out + ((size_t)(n0 + l15) * T + t) * 256 + d * 128 + j0) = o4;
        if (have_next) { xr_c = xr_n; xz_c = xz_n; xn_c = xn_n; }
        bar_lds();
    }
}

// ---------------------------------------------------------------------------
// Word attention fused: proj GEMM + tanh.ctx scores + softmax + pool.
// ---------------------------------------------------------------------------
#define SP 264
__global__ __launch_bounds__(256) void word_attn_kernel(const ushort_t* __restrict__ wout,
                                                        const ushort_t* __restrict__ W,
                                                        const ushort_t* __restrict__ bias,
                                                        const ushort_t* __restrict__ ctx,
                                                        const int* __restrict__ dmax,
                                                        ushort_t* __restrict__ sent) {
    __shared__ ushort_t tile[64 * SP];
    __shared__ float bc[256];
    __shared__ float sc_lds[64];
    __shared__ float p_lds[64];
    int tid = threadIdx.x, g = blockIdx.x;
    for (int idx = tid; idx < 2048; idx += 256) {
        int row = idx >> 5, k0 = (idx & 31) * 8;
        *(uint4*)&tile[row * SP + k0] = *(const uint4*)(wout + ((size_t)g * 64 + row) * 256 + k0);
    }
    if (tid < 128) bc[tid] = bf2f(bias[tid]);
    else bc[tid] = bf2f(ctx[tid - 128]);
    __syncthreads();
    int lane = tid & 63, wave = tid >> 6;
    int l15 = lane & 15, l4 = (lane >> 4) & 3;
    short8 a[8];
    #pragma unroll
    for (int kf = 0; kf < 8; ++kf)
        a[kf] = *(const short8*)&tile[(wave * 16 + l15) * SP + kf * 32 + l4 * 8];
    floatx4 acc[8];
    #pragma unroll
    for (int nt = 0; nt < 8; ++nt) {
        floatx4 c = {0.f, 0.f, 0.f, 0.f};
        #pragma unroll
        for (int kf = 0; kf < 8; ++kf) {
            short8 b = *(const short8*)(W + (size_t)(nt * 16 + l15) * 256 + kf * 32 + l4 * 8);
            c = MFMA16(a[kf], b, c);
        }
        acc[nt] = c;
    }
    float s[4] = {0.f, 0.f, 0.f, 0.f};
    #pragma unroll
    for (int nt = 0; nt < 8; ++nt) {
        float bv = bc[nt * 16 + l15], cv = bc[128 + nt * 16 + l15];
        #pragma unroll
        for (int i = 0; i < 4; ++i)
            s[i] += ftanh(acc[nt][i] + bv) * cv;
    }
    #pragma unroll
    for (int i = 0; i < 4; ++i) {
        s[i] += __shfl_xor(s[i], 1);
        s[i] += __shfl_xor(s[i], 2);
        s[i] += __shfl_xor(s[i], 4);
        s[i] += __shfl_xor(s[i], 8);
    }
    if (l15 == 0) {
        #pragma unroll
        for (int i = 0; i < 4; ++i) sc_lds[wave * 16 + l4 * 4 + i] = s[i];
    }
    __syncthreads();
    if (tid < 64) {
        int ml = dmax[tid & 31];
        for (int off = 32; off; off >>= 1) ml = max(ml, __shfl_xor(ml, off));
        bool v = tid < ml;
        float sc = v ? sc_lds[tid] : -1e30f;
        float mx = sc;
        for (int off = 32; off; off >>= 1) mx = fmaxf(mx, __shfl_xor(mx, off));
        float e = v ? __expf(sc - mx) : 0.f;
        float sum = e;
        for (int off = 32; off; off >>= 1) sum += __shfl_xor(sum, off);
        p_lds[tid] = e / fmaxf(sum, 1e-30f);
    }
    __syncthreads();
    float acc2 = 0.f;
    for (int t = 0; t < 64; ++t) acc2 += p_lds[t] * bf2f(tile[t * SP + tid]);
    sent[(size_t)g * 256 + tid] = f2bf(acc2);
}

// ---------------------------------------------------------------------------
// Sentence attention + FC fused. grid 32 (per doc); 256 thr. Writes d_out.
// ---------------------------------------------------------------------------
__global__ __launch_bounds__(256) void sent_attn_fc_kernel(const ushort_t* __restrict__ sout,
                                                           const ushort_t* __restrict__ W,
                                                           const ushort_t* __restrict__ bias,
                                                           const ushort_t* __restrict__ ctx,
                                                           const ushort_t* __restrict__ fcW,
                                                           const ushort_t* __restrict__ fcb,
                                                           const int* __restrict__ slens,
                                                           const int* __restrict__ flagp,
                                                           void* __restrict__ outp) {
    __shared__ ushort_t tile[32 * SP];
    __shared__ float bc[256];
    __shared__ float sc_lds[32];
    __shared__ float p_lds[32];
    __shared__ float dv[256];
    int tid = threadIdx.x, g = blockIdx.x;
    for (int idx = tid; idx < 1024; idx += 256) {
        int row = idx >> 5, k0 = (idx & 31) * 8;
        *(uint4*)&tile[row * SP + k0] = *(const uint4*)(sout + ((size_t)g * 32 + row) * 256 + k0);
    }
    if (tid < 128) bc[tid] = bf2f(bias[tid]);
    else bc[tid] = bf2f(ctx[tid - 128]);
    __syncthreads();
    int lane = tid & 63, wave = tid >> 6;
    int l15 = lane & 15, l4 = (lane >> 4) & 3;
    if (wave < 2) {
        short8 a[8];
        #pragma unroll
        for (int kf = 0; kf < 8; ++kf)
            a[kf] = *(const short8*)&tile[(wave * 16 + l15) * SP + kf * 32 + l4 * 8];
        floatx4 acc[8];
        #pragma unroll
        for (int nt = 0; nt < 8; ++nt) {
            floatx4 c = {0.f, 0.f, 0.f, 0.f};
            #pragma unroll
            for (int kf = 0; kf < 8; ++kf) {
                short8 b = *(const short8*)(W + (size_t)(nt * 16 + l15) * 256 + kf * 32 + l4 * 8);
                c = MFMA16(a[kf], b, c);
            }
            acc[nt] = c;
        }
        float s[4] = {0.f, 0.f, 0.f, 0.f};
        #pragma unroll
        for (int nt = 0; nt < 8; ++nt) {
            float bv = bc[nt * 16 + l15], cv = bc[128 + nt * 16 + l15];
            #pragma unroll
            for (int i = 0; i < 4; ++i)
                s[i] += ftanh(acc[nt][i] + bv) * cv;
        }
        #pragma unroll
        for (int i = 0; i < 4; ++i) {
            s[i] += __shfl_xor(s[i], 1);
            s[i] += __shfl_xor(s[i], 2);
            s[i] += __shfl_xor(s[i], 4);
            s[i] += __shfl_xor(s[i], 8);
        }
        if (l15 == 0) {
            #pragma unroll
            for (int i = 0; i < 4; ++i) sc_lds[wave * 16 + l4 * 4 + i] = s[i];
        }
    }
    __syncthreads();
    if (tid < 32) {
        int ml = slens[tid];
        for (int off = 16; off; off >>= 1) ml = max(ml, __shfl_xor(ml, off, 32));
        bool v = tid < ml;
        float sc = v ? sc_lds[tid] : -1e30f;
        float mx = sc;
        for (int off = 16; off; off >>= 1) mx = fmaxf(mx, __shfl_xor(mx, off, 32));
        float e = v ? __expf(sc - mx) : 0.f;
        float sum = e;
        for (int off = 16; off; off >>= 1) sum += __shfl_xor(sum, off, 32);
        p_lds[tid] = e / fmaxf(sum, 1e-30f);
    }
    __syncthreads();
    float acc2 = 0.f;
    for (int t = 0; t < 32; ++t) acc2 += p_lds[t] * bf2f(tile[t * SP + tid]);
    dv[tid] = acc2;
    __syncthreads();
    int c = tid >> 5, q0 = (tid & 31) * 8;
    float partial = 0.f;
    #pragma unroll
    for (int q = 0; q < 8; ++q)
        partial += dv[q0 + q] * bf2f(fcW[(size_t)c * 256 + q0 + q]);
    for (int off = 16; off; off >>= 1) partial += __shfl_xor(partial, off, 32);
    if ((tid & 31) == 0) {
        float v = partial + bf2f(fcb[c]);
        if (*flagp) ((float*)outp)[g * 8 + c] = v;
        else        ((ushort_t*)outp)[g * 8 + c] = f2bf(v);
    }
}

// ---------------------------------------------------------------------------
extern "C" void kernel_launch(void* const* d_in, const int* in_sizes, int n_in,
                              void* d_out, int out_size, void* d_ws, size_t ws_size,
                              hipStream_t stream) {
    const int* x = (const int*)d_in[0];
    char* ws = (char*)d_ws;

    const size_t O_CONV = 0;            // canonical bf16 inputs (~14 MB)
    const size_t O_WOUT = 14680064;     // [65536,256] bf16  33.55 MB
    const size_t O_SENT = 48234496;     // [1024,256] bf16
    const size_t O_SOUT = 48758784;     // [1024,256] bf16
    const size_t O_SPTF = 49283072;     // spT fwd [2*32*96*64] bf16 1.5MB
    const size_t O_SPTB = 50855936;     // spT bwd
    const size_t O_LENS = 52428800;     // wlens [1024] int
    const size_t O_SLEN = 52432896;     // slens [32] int
    const size_t O_DMAX = 52433024;     // per-doc word-len maxima [32] int
    const size_t O_FLAG = 52433152;

    ushort_t* conv = (ushort_t*)(ws + O_CONV);
    ushort_t* wout = (ushort_t*)(ws + O_WOUT);
    ushort_t* sent = (ushort_t*)(ws + O_SENT);
    ushort_t* sout = (ushort_t*)(ws + O_SOUT);
    ushort_t* sptf = (ushort_t*)(ws + O_SPTF);
    ushort_t* sptb = (ushort_t*)(ws + O_SPTB);
    int* wlens = (int*)(ws + O_LENS);
    int* slens = (int*)(ws + O_SLEN);
    int* dmax  = (int*)(ws + O_DMAX);
    int* flag  = (int*)(ws + O_FLAG);

    ConvArgs ca;
    ushort_t* cw[25];
    int off = 0, blk = 0;
    for (int i = 1; i <= 25; ++i) {
        int j = i - 1;
        int cnt = in_sizes[i];
        ca.src[j] = d_in[i];
        ca.dstoff[j] = off;
        ca.count[j] = cnt;
        ca.cumblk[j] = blk;
        cw[j] = conv + off;
        off += cnt;
        blk += (cnt + 2047) / 2048;
    }
    ca.cumblk[25] = blk;

    // 1) lengths + dtype detect (33 blocks)
    lens_kernel<<<33, 64, 0, stream>>>(x, (const unsigned int*)d_in[1],
                                       wlens, slens, dmax, flag);
    // 2) canonicalize float inputs -> bf16
    convert_kernel<<<blk, 256, 0, stream>>>(ca, conv, flag);
    // 3) word BiGRU (register x-fragments, no LDS x staging)
    word_gru_kernel<<<dim3(64, 2), 512, 0, stream>>>(
        x, cw[0],
        cw[1], cw[2], cw[3], cw[4],      // wf: Wih, Whh, bih, bhh
        cw[5], cw[6], cw[7], cw[8],      // wb
        wlens, wout);
    // 4) word attention fused -> sent
    word_attn_kernel<<<1024, 256, 0, stream>>>(wout, cw[17], cw[18], cw[19], dmax, sent);
    // 5) sentence xp -> transposed spT (both dirs)
    spt_gemm_kernel<<<dim3(16, 12), 256, 0, stream>>>(sent, cw[9], cw[11], sptf,
                                                      cw[13], cw[15], sptb);
    // 6) sentence BiGRU (lean: h-only MFMAs, register xp prefetch)
    sent_gru_kernel<<<dim3(2, 2), 512, 0, stream>>>(
        sptf, sptb, cw[10], cw[14], cw[12], cw[16], slens, sout);
    // 7) sentence attention + FC -> d_out
    sent_attn_fc_kernel<<<32, 256, 0, stream>>>(sout, cw[20], cw[21], cw[22],
                                                cw[23], cw[24], slens, flag, d_out);
    (void)n_in; (void)out_size; (void)ws_size;
}

// Round 9
// 316.773 us; speedup vs baseline: 1.0065x; 1.0065x over previous
//
#include <hip/hip_runtime.h>
#include <hip/hip_bf16.h>

typedef unsigned short ushort_t;
typedef __attribute__((ext_vector_type(4))) float floatx4;
typedef __attribute__((ext_vector_type(8))) short short8;

__device__ __forceinline__ float bf2f(ushort_t u) {
    union { unsigned int i; float f; } v; v.i = ((unsigned int)u) << 16; return v.f;
}
__device__ __forceinline__ ushort_t f2bf(float f) {
    union { float f; unsigned int i; } v; v.f = f;
    unsigned int i = v.i;
    i += 0x7fffu + ((i >> 16) & 1u);            // RNE
    return (ushort_t)(i >> 16);
}
__device__ __forceinline__ float fsig(float x)  { return 1.f / (1.f + __expf(-x)); }
__device__ __forceinline__ float ftanh(float x) { return 1.f - 2.f / (__expf(2.f * x) + 1.f); }

__device__ __forceinline__ floatx4 MFMA16(short8 a, short8 b, floatx4 c) {
    return __builtin_amdgcn_mfma_f32_16x16x32_bf16(a, b, c, 0, 0, 0);
}

// LDS-only barrier, CK-style: intrinsic waitcnt (lgkmcnt(0) ONLY — vmcnt and
// expcnt fields maxed) + raw s_barrier. No asm "memory" clobber, so the
// compiler does NOT drain vmcnt: global stores & prefetch loads stay in
// flight across the barrier. (The prior asm-clobber version forced a full
// vmcnt(0) drain per step — that was the hidden stall in rounds 5-8.)
__device__ __forceinline__ void bar_lds() {
    __builtin_amdgcn_s_waitcnt(0xc07f);   // vmcnt=63, expcnt=7, lgkmcnt=0
    __builtin_amdgcn_s_barrier();
}

// Swizzled LDS index for [chunk c][seq m][8 elems] bf16 tiles.
#define XIDX(c, m) ((((c) * 16) + ((m) ^ ((c) & 15))) * 8)

// ---------------------------------------------------------------------------
// K1: lengths + dtype detect. Blocks 0..31: per-doc lens + dmax (race-free).
// Block 32: dtype detection on raw emb words.
// ---------------------------------------------------------------------------
__global__ __launch_bounds__(64) void lens_kernel(const int* __restrict__ x,
                                                  const unsigned int* __restrict__ raw,
                                                  int* wlens, int* slens, int* dmax,
                                                  int* flag) {
    int b = blockIdx.x, s = threadIdx.x;
    if (b == 32) {
        int c = 0;
        for (int i = 0; i < 16; ++i) {
            unsigned int v = raw[s * 16 + i];
            unsigned int e = (v >> 7) & 0xFFu;   // low-ushort bf16 exponent field
            if (e > 0x7Bu) ++c;
        }
        c += __shfl_xor(c, 1);  c += __shfl_xor(c, 2);  c += __shfl_xor(c, 4);
        c += __shfl_xor(c, 8);  c += __shfl_xor(c, 16); c += __shfl_xor(c, 32);
        if (s == 0) *flag = (c > 64) ? 1 : 0;    // 1 => inputs are f32
        return;
    }
    int last = 0;
    if (s < 32) {
        const int* tok = x + (b * 32 + s) * 64;
        for (int t = 0; t < 64; t += 4) {
            int4 v = *(const int4*)(tok + t);
            if (v.x) last = t + 1;
            if (v.y) last = t + 2;
            if (v.z) last = t + 3;
            if (v.w) last = t + 4;
        }
        wlens[b * 32 + s] = last ? last : 1;
    }
    int len = (s < 32) ? (last ? last : 1) : 0;
    int lm = len;
    for (int off = 32; off; off >>= 1) lm = max(lm, __shfl_xor(lm, off));
    unsigned long long mask = __ballot(s < 32 && last > 0);
    if (s == 0) {
        slens[b] = mask ? (63 - (int)__clzll(mask) + 1) : 1;
        dmax[b] = lm;
    }
}

// ---------------------------------------------------------------------------
// K0b: canonicalize all float inputs to bf16 in ws.
// ---------------------------------------------------------------------------
struct ConvArgs {
    const void* src[25];
    int dstoff[25];
    int count[25];
    int cumblk[26];
};

__global__ __launch_bounds__(256) void convert_kernel(ConvArgs a, ushort_t* __restrict__ dst,
                                                      const int* __restrict__ flag) {
    int b = blockIdx.x;
    int lo = 0, hi = 24;
    while (lo < hi) { int mid = (lo + hi + 1) >> 1; if (a.cumblk[mid] <= b) lo = mid; else hi = mid - 1; }
    int j = lo;
    size_t base = (size_t)(b - a.cumblk[j]) * 2048 + (size_t)threadIdx.x * 8;
    if (base >= (size_t)a.count[j]) return;
    ushort_t* out = dst + a.dstoff[j] + base;
    if (*flag) {
        const float* s = (const float*)a.src[j] + base;
        float4 v0 = *(const float4*)s;
        float4 v1 = *(const float4*)(s + 4);
        union { ushort_t u[8]; uint4 v; } o;
        o.u[0] = f2bf(v0.x); o.u[1] = f2bf(v0.y); o.u[2] = f2bf(v0.z); o.u[3] = f2bf(v0.w);
        o.u[4] = f2bf(v1.x); o.u[5] = f2bf(v1.y); o.u[6] = f2bf(v1.z); o.u[7] = f2bf(v1.w);
        *(uint4*)out = o.v;
    } else {
        *(uint4*)out = *(const uint4*)((const ushort_t*)a.src[j] + base);
    }
}

// ---------------------------------------------------------------------------
// Word-level BiGRU: fused gather+proj+recurrence, in-register gates.
// grid (64, 2); 512 thr. x B-fragments loaded directly from emb into registers.
// h double-buffered in LDS; TRUE LDS-only barrier per step.
// ---------------------------------------------------------------------------
__global__ __launch_bounds__(512, 2) void word_gru_kernel(
        const int* __restrict__ x, const ushort_t* __restrict__ emb,
        const ushort_t* __restrict__ Wih_f, const ushort_t* __restrict__ Whh_f,
        const ushort_t* __restrict__ bih_f, const ushort_t* __restrict__ bhh_f,
        const ushort_t* __restrict__ Wih_b, const ushort_t* __restrict__ Whh_b,
        const ushort_t* __restrict__ bih_b, const ushort_t* __restrict__ bhh_b,
        const int* __restrict__ lens, ushort_t* __restrict__ out) {
    const int T = 64;
    __shared__ ushort_t h_buf[2][2048];      // swizzled [k/8][m(16)][8] bf16
    __shared__ float bsum_lds[256];
    __shared__ float bihn_lds[128];
    __shared__ float bhhn_lds[128];
    __shared__ int tok_lds[1024];            // TRANSPOSED [t][s] (bank-friendly)

    int tid = threadIdx.x;
    int d = blockIdx.y;
    int n0 = blockIdx.x * 16;
    const ushort_t* Wih = d ? Wih_b : Wih_f;
    const ushort_t* Whh = d ? Whh_b : Whh_f;
    const ushort_t* bih = d ? bih_b : bih_f;
    const ushort_t* bhh = d ? bhh_b : bhh_f;
    int lane = tid & 63, wave = tid >> 6;
    int l15 = lane & 15, l4 = (lane >> 4) & 3;
    int jt = wave * 16;
    int j0 = jt + l4 * 4;

    for (int i = tid; i < 1024; i += 512) {
        int t = i >> 4, s = i & 15;
        tok_lds[i] = x[(n0 + s) * 64 + t];
    }
    if (tid < 256) bsum_lds[tid] = bf2f(bih[tid]) + bf2f(bhh[tid]);
    else if (tid < 384) {
        bihn_lds[tid - 256] = bf2f(bih[tid]);
        bhhn_lds[tid - 256] = bf2f(bhh[tid]);
    }
    { uint2 z = {0u, 0u}; *(uint2*)&h_buf[0][tid * 4] = z; }

    short8 wr[4], wz[4], wn[4], ur[4], uz[4], un[4];
    #pragma unroll
    for (int kf = 0; kf < 4; ++kf) {
        int col = kf * 32 + l4 * 8;
        wr[kf] = *(const short8*)(Wih + (size_t)(jt + l15) * 128 + col);
        wz[kf] = *(const short8*)(Wih + (size_t)(128 + jt + l15) * 128 + col);
        wn[kf] = *(const short8*)(Wih + (size_t)(256 + jt + l15) * 128 + col);
        ur[kf] = *(const short8*)(Whh + (size_t)(jt + l15) * 128 + col);
        uz[kf] = *(const short8*)(Whh + (size_t)(128 + jt + l15) * 128 + col);
        un[kf] = *(const short8*)(Whh + (size_t)(256 + jt + l15) * 128 + col);
    }
    __syncthreads();                         // tok_lds + biases + h zero ready

    floatx4 br  = *(floatx4*)&bsum_lds[j0];
    floatx4 bz  = *(floatx4*)&bsum_lds[128 + j0];
    floatx4 bxn = *(floatx4*)&bihn_lds[j0];
    floatx4 bhn = *(floatx4*)&bhhn_lds[j0];
    int lv = lens[n0 + l15];
    float hreg[4] = {0.f, 0.f, 0.f, 0.f};

    // x B-fragment for this lane: emb[tok[l15][t]][kf*32 + l4*8 .. +7]
    short8 xc[4], xn_[4];
    {
        int t0 = d ? (T - 1) : 0;
        size_t rb = (size_t)tok_lds[t0 * 16 + l15] * 128 + l4 * 8;
        #pragma unroll
        for (int kf = 0; kf < 4; ++kf)
            xc[kf] = *(const short8*)(emb + rb + kf * 32);
    }

    for (int ti = 0; ti < T; ++ti) {
        int t = d ? (T - 1 - ti) : ti;
        bool have_next = (ti + 1) < T;
        if (have_next) {                     // issue next x-frag loads early
            int tn = d ? (T - 2 - ti) : (ti + 1);
            size_t rb = (size_t)tok_lds[tn * 16 + l15] * 128 + l4 * 8;
            #pragma unroll
            for (int kf = 0; kf < 4; ++kf)
                xn_[kf] = *(const short8*)(emb + rb + kf * 32);
        }
        short8 hb[4];
        #pragma unroll
        for (int kf = 0; kf < 4; ++kf)
            hb[kf] = *(const short8*)&h_buf[ti & 1][XIDX(kf * 4 + l4, l15)];
        floatx4 arx = br, azx = bz, axn = bxn;
        floatx4 arh = {0.f, 0.f, 0.f, 0.f}, azh = {0.f, 0.f, 0.f, 0.f}, ahn = bhn;
        #pragma unroll
        for (int kf = 0; kf < 4; ++kf) {
            arx = MFMA16(wr[kf], xc[kf], arx);
            azx = MFMA16(wz[kf], xc[kf], azx);
            axn = MFMA16(wn[kf], xc[kf], axn);
        }
        #pragma unroll
        for (int kf = 0; kf < 4; ++kf) {
            arh = MFMA16(ur[kf], hb[kf], arh);
            azh = MFMA16(uz[kf], hb[kf], azh);
            ahn = MFMA16(un[kf], hb[kf], ahn);
        }
        bool valid = t < lv;
        ushort_t hu[4], ou[4];
        #pragma unroll
        for (int i = 0; i < 4; ++i) {
            float r  = fsig(arx[i] + arh[i]);
            float z  = fsig(azx[i] + azh[i]);
            float nn = ftanh(axn[i] + r * ahn[i]);
            float hv = valid ? (nn + z * (hreg[i] - nn)) : hreg[i];
            hreg[i] = hv;
            hu[i] = f2bf(hv);
            ou[i] = valid ? hu[i] : (ushort_t)0;
        }
        ushort4 h4; h4.x = hu[0]; h4.y = hu[1]; h4.z = hu[2]; h4.w = hu[3];
        ushort4 o4; o4.x = ou[0]; o4.y = ou[1]; o4.z = ou[2]; o4.w = ou[3];
        *(ushort4*)&h_buf[(ti & 1) ^ 1][XIDX(j0 >> 3, l15) + (j0 & 7)] = h4;
        *(ushort4*)(out + ((size_t)(n0 + l15) * T + t) * 256 + d * 128 + j0) = o4;
        if (have_next) {
            #pragma unroll
            for (int kf = 0; kf < 4; ++kf) xc[kf] = xn_[kf];
        }
        bar_lds();
    }
}

// ---------------------------------------------------------------------------
// Sentence xp GEMM -> transposed layout spT.
// spT element (doc, t, n) stored at [(dblk*32 + t)*96 + (n>>2)]*64 + (doc&15)*4 + (n&3)
// where dblk = doc>>4. grid (16, 12): by<6 fwd n-tiles, by>=6 bwd.
// ---------------------------------------------------------------------------
__global__ __launch_bounds__(256) void spt_gemm_kernel(const ushort_t* __restrict__ A,
                                                       const ushort_t* __restrict__ Bf_,
                                                       const ushort_t* __restrict__ biasf,
                                                       ushort_t* __restrict__ Tf_,
                                                       const ushort_t* __restrict__ Bb_,
                                                       const ushort_t* __restrict__ biasb,
                                                       ushort_t* __restrict__ Tb_) {
    __shared__ ushort_t As[64 * 256];
    __shared__ ushort_t Bs[64 * 256];
    const int K = 256;
    int tid = threadIdx.x;
    int by = blockIdx.y;
    bool sb = by >= 6;
    int n0 = (sb ? by - 6 : by) * 64;
    const ushort_t* B = sb ? Bb_ : Bf_;
    const ushort_t* bias = sb ? biasb : biasf;
    ushort_t* Tp = sb ? Tb_ : Tf_;
    int m0 = blockIdx.x * 64;
    for (int idx = tid; idx < 2048; idx += 256) {
        int m = idx & 63, c = idx >> 6;
        *(uint4*)&As[(c * 64 + m) * 8] = *(const uint4*)(A + (size_t)(m0 + m) * K + c * 8);
    }
    for (int idx = tid; idx < 2048; idx += 256) {
        int n = idx & 63, c = idx >> 6;
        *(uint4*)&Bs[(c * 64 + n) * 8] = *(const uint4*)(B + (size_t)(n0 + n) * K + c * 8);
    }
    __syncthreads();
    int lane = tid & 63, wave = tid >> 6;
    int wm = (wave & 1) * 32, wn = (wave >> 1) * 32;
    int l15 = lane & 15, l4 = lane >> 4;
    floatx4 acc[2][2] = {};
    for (int kf = 0; kf < 8; ++kf) {
        int c = kf * 4 + l4;
        short8 a0 = *(const short8*)&As[(c * 64 + wm + l15) * 8];
        short8 a1 = *(const short8*)&As[(c * 64 + wm + 16 + l15) * 8];
        short8 b0 = *(const short8*)&Bs[(c * 64 + wn + l15) * 8];
        short8 b1 = *(const short8*)&Bs[(c * 64 + wn + 16 + l15) * 8];
        acc[0][0] = MFMA16(a0, b0, acc[0][0]);
        acc[0][1] = MFMA16(a0, b1, acc[0][1]);
        acc[1][0] = MFMA16(a1, b0, acc[1][0]);
        acc[1][1] = MFMA16(a1, b1, acc[1][1]);
    }
    for (int nt = 0; nt < 2; ++nt) {
        int n = n0 + wn + nt * 16 + l15;
        float bv = bf2f(bias[n]);
        int jc = n >> 2, ji = n & 3;
        for (int mt = 0; mt < 2; ++mt) {
            int mbase = m0 + wm + mt * 16 + l4 * 4;
            #pragma unroll
            for (int i = 0; i < 4; ++i) {
                int m = mbase + i;                  // global sent row = doc*32 + t
                int doc = m >> 5, t = m & 31;
                size_t dst = ((size_t)((doc >> 4) * 32 + t) * 96 + jc) * 64
                           + (doc & 15) * 4 + ji;
                Tp[dst] = f2bf(acc[mt][nt][i] + bv);
            }
        }
    }
}

// ---------------------------------------------------------------------------
// Sentence-level BiGRU (lean): h-only MFMAs; xp read from spT with coalesced
// register prefetch (1 step ahead). grid (2, 2); 512 thr; T=32.
// ---------------------------------------------------------------------------
__global__ __launch_bounds__(512, 1) void sent_gru_kernel(
        const ushort_t* __restrict__ spT_f, const ushort_t* __restrict__ spT_b,
        const ushort_t* __restrict__ Whh_f, const ushort_t* __restrict__ Whh_b,
        const ushort_t* __restrict__ bhh_f, const ushort_t* __restrict__ bhh_b,
        const int* __restrict__ lens, ushort_t* __restrict__ out) {
    const int T = 32;
    __shared__ ushort_t h_buf[2][2048];      // swizzled [k/8][m][8]
    __shared__ float bhh_lds[384];

    int tid = threadIdx.x;
    int d = blockIdx.y;
    int n0 = blockIdx.x * 16;
    const ushort_t* spT = d ? spT_b : spT_f;
    const ushort_t* Whh = d ? Whh_b : Whh_f;
    const ushort_t* bhh = d ? bhh_b : bhh_f;
    int lane = tid & 63, wave = tid >> 6;
    int l15 = lane & 15, l4 = (lane >> 4) & 3;
    int jt = wave * 16;
    int j0 = jt + l4 * 4;
    int jc = j0 >> 2;

    if (tid < 384) bhh_lds[tid] = bf2f(bhh[tid]);
    { uint2 z = {0u, 0u}; *(uint2*)&h_buf[0][tid * 4] = z; }

    short8 ur[4], uz[4], un[4];
    #pragma unroll
    for (int kf = 0; kf < 4; ++kf) {
        int col = kf * 32 + l4 * 8;
        ur[kf] = *(const short8*)(Whh + (size_t)(jt + l15) * 128 + col);
        uz[kf] = *(const short8*)(Whh + (size_t)(128 + jt + l15) * 128 + col);
        un[kf] = *(const short8*)(Whh + (size_t)(256 + jt + l15) * 128 + col);
    }
    __syncthreads();

    floatx4 br  = *(floatx4*)&bhh_lds[j0];
    floatx4 bz  = *(floatx4*)&bhh_lds[128 + j0];
    floatx4 bhn = *(floatx4*)&bhh_lds[256 + j0];
    int lv = lens[n0 + l15];
    float hreg[4] = {0.f, 0.f, 0.f, 0.f};

    // spT base for this block: dblk = n0/16
    const ushort_t* sp = spT + (size_t)(blockIdx.x * 32) * 96 * 64 + l15 * 4;
    ushort4 xr_c, xz_c, xn_c, xr_n, xz_n, xn_n;
    {
        int t0 = d ? (T - 1) : 0;
        size_t rb = (size_t)t0 * 96 * 64;
        xr_c = *(const ushort4*)(sp + rb + (size_t)jc * 64);
        xz_c = *(const ushort4*)(sp + rb + (size_t)(32 + jc) * 64);
        xn_c = *(const ushort4*)(sp + rb + (size_t)(64 + jc) * 64);
    }

    for (int ti = 0; ti < T; ++ti) {
        int t = d ? (T - 1 - ti) : ti;
        int cur = ti & 1;
        bool have_next = (ti + 1) < T;
        if (have_next) {
            int tn = d ? (T - 2 - ti) : (ti + 1);
            size_t rb = (size_t)tn * 96 * 64;
            xr_n = *(const ushort4*)(sp + rb + (size_t)jc * 64);
            xz_n = *(const ushort4*)(sp + rb + (size_t)(32 + jc) * 64);
            xn_n = *(const ushort4*)(sp + rb + (size_t)(64 + jc) * 64);
        }
        floatx4 ar = br, az = bz, ahn = bhn;
        #pragma unroll
        for (int kf = 0; kf < 4; ++kf) {
            short8 hb = *(const short8*)&h_buf[cur][XIDX(kf * 4 + l4, l15)];
            ar  = MFMA16(ur[kf], hb, ar);
            az  = MFMA16(uz[kf], hb, az);
            ahn = MFMA16(un[kf], hb, ahn);
        }
        float xr[4] = {bf2f(xr_c.x), bf2f(xr_c.y), bf2f(xr_c.z), bf2f(xr_c.w)};
        float xz[4] = {bf2f(xz_c.x), bf2f(xz_c.y), bf2f(xz_c.z), bf2f(xz_c.w)};
        float xn[4] = {bf2f(xn_c.x), bf2f(xn_c.y), bf2f(xn_c.z), bf2f(xn_c.w)};
        bool valid = t < lv;
        ushort_t hu[4], ou[4];
        #pragma unroll
        for (int i = 0; i < 4; ++i) {
            float r  = fsig(xr[i] + ar[i]);
            float z  = fsig(xz[i] + az[i]);
            float nn = ftanh(xn[i] + r * ahn[i]);
            float hv = valid ? (nn + z * (hreg[i] - nn)) : hreg[i];
            hreg[i] = hv;
            hu[i] = f2bf(hv);
            ou[i] = valid ? hu[i] : (ushort_t)0;
        }
        ushort4 h4; h4.x = hu[0]; h4.y = hu[1]; h4.z = hu[2]; h4.w = hu[3];
        ushort4 o4; o4.x = ou[0]; o4.y = ou[1]; o4.z = ou[2]; o4.w = ou[3];
        *(ushort4*)&h_buf[cur ^ 1][XIDX(j0 >> 3, l15) + (j0 & 7)] = h4;
        *(ushort4*)(out + ((size_t)(n0 + l15) * T + t) * 256 + d * 128 + j0) = o4;
        if (have_next) { xr_c = xr_n; xz_c = xz_n; xn_c = xn_n; }
        bar_lds();
    }
}

// ---------------------------------------------------------------------------
// Word attention fused: proj GEMM + tanh.ctx scores + softmax + pool.
// ---------------------------------------------------------------------------
#define SP 264
__global__ __launch_bounds__(256) void word_attn_kernel(const ushort_t* __restrict__ wout,
                                                        const ushort_t* __restrict__ W,
                                                        const ushort_t* __restrict__ bias,
                                                        const ushort_t* __restrict__ ctx,
                                                        const int* __restrict__ dmax,
                                                        ushort_t* __restrict__ sent) {
    __shared__ ushort_t tile[64 * SP];
    __shared__ float bc[256];
    __shared__ float sc_lds[64];
    __shared__ float p_lds[64];
    int tid = threadIdx.x, g = blockIdx.x;
    for (int idx = tid; idx < 2048; idx += 256) {
        int row = idx >> 5, k0 = (idx & 31) * 8;
        *(uint4*)&tile[row * SP + k0] = *(const uint4*)(wout + ((size_t)g * 64 + row) * 256 + k0);
    }
    if (tid < 128) bc[tid] = bf2f(bias[tid]);
    else bc[tid] = bf2f(ctx[tid - 128]);
    __syncthreads();
    int lane = tid & 63, wave = tid >> 6;
    int l15 = lane & 15, l4 = (lane >> 4) & 3;
    short8 a[8];
    #pragma unroll
    for (int kf = 0; kf < 8; ++kf)
        a[kf] = *(const short8*)&tile[(wave * 16 + l15) * SP + kf * 32 + l4 * 8];
    floatx4 acc[8];
    #pragma unroll
    for (int nt = 0; nt < 8; ++nt) {
        floatx4 c = {0.f, 0.f, 0.f, 0.f};
        #pragma unroll
        for (int kf = 0; kf < 8; ++kf) {
            short8 b = *(const short8*)(W + (size_t)(nt * 16 + l15) * 256 + kf * 32 + l4 * 8);
            c = MFMA16(a[kf], b, c);
        }
        acc[nt] = c;
    }
    float s[4] = {0.f, 0.f, 0.f, 0.f};
    #pragma unroll
    for (int nt = 0; nt < 8; ++nt) {
        float bv = bc[nt * 16 + l15], cv = bc[128 + nt * 16 + l15];
        #pragma unroll
        for (int i = 0; i < 4; ++i)
            s[i] += ftanh(acc[nt][i] + bv) * cv;
    }
    #pragma unroll
    for (int i = 0; i < 4; ++i) {
        s[i] += __shfl_xor(s[i], 1);
        s[i] += __shfl_xor(s[i], 2);
        s[i] += __shfl_xor(s[i], 4);
        s[i] += __shfl_xor(s[i], 8);
    }
    if (l15 == 0) {
        #pragma unroll
        for (int i = 0; i < 4; ++i) sc_lds[wave * 16 + l4 * 4 + i] = s[i];
    }
    __syncthreads();
    if (tid < 64) {
        int ml = dmax[tid & 31];
        for (int off = 32; off; off >>= 1) ml = max(ml, __shfl_xor(ml, off));
        bool v = tid < ml;
        float sc = v ? sc_lds[tid] : -1e30f;
        float mx = sc;
        for (int off = 32; off; off >>= 1) mx = fmaxf(mx, __shfl_xor(mx, off));
        float e = v ? __expf(sc - mx) : 0.f;
        float sum = e;
        for (int off = 32; off; off >>= 1) sum += __shfl_xor(sum, off);
        p_lds[tid] = e / fmaxf(sum, 1e-30f);
    }
    __syncthreads();
    float acc2 = 0.f;
    for (int t = 0; t < 64; ++t) acc2 += p_lds[t] * bf2f(tile[t * SP + tid]);
    sent[(size_t)g * 256 + tid] = f2bf(acc2);
}

// ---------------------------------------------------------------------------
// Sentence attention + FC fused. grid 32 (per doc); 256 thr. Writes d_out.
// ---------------------------------------------------------------------------
__global__ __launch_bounds__(256) void sent_attn_fc_kernel(const ushort_t* __restrict__ sout,
                                                           const ushort_t* __restrict__ W,
                                                           const ushort_t* __restrict__ bias,
                                                           const ushort_t* __restrict__ ctx,
                                                           const ushort_t* __restrict__ fcW,
                                                           const ushort_t* __restrict__ fcb,
                                                           const int* __restrict__ slens,
                                                           const int* __restrict__ flagp,
                                                           void* __restrict__ outp) {
    __shared__ ushort_t tile[32 * SP];
    __shared__ float bc[256];
    __shared__ float sc_lds[32];
    __shared__ float p_lds[32];
    __shared__ float dv[256];
    int tid = threadIdx.x, g = blockIdx.x;
    for (int idx = tid; idx < 1024; idx += 256) {
        int row = idx >> 5, k0 = (idx & 31) * 8;
        *(uint4*)&tile[row * SP + k0] = *(const uint4*)(sout + ((size_t)g * 32 + row) * 256 + k0);
    }
    if (tid < 128) bc[tid] = bf2f(bias[tid]);
    else bc[tid] = bf2f(ctx[tid - 128]);
    __syncthreads();
    int lane = tid & 63, wave = tid >> 6;
    int l15 = lane & 15, l4 = (lane >> 4) & 3;
    if (wave < 2) {
        short8 a[8];
        #pragma unroll
        for (int kf = 0; kf < 8; ++kf)
            a[kf] = *(const short8*)&tile[(wave * 16 + l15) * SP + kf * 32 + l4 * 8];
        floatx4 acc[8];
        #pragma unroll
        for (int nt = 0; nt < 8; ++nt) {
            floatx4 c = {0.f, 0.f, 0.f, 0.f};
            #pragma unroll
            for (int kf = 0; kf < 8; ++kf) {
                short8 b = *(const short8*)(W + (size_t)(nt * 16 + l15) * 256 + kf * 32 + l4 * 8);
                c = MFMA16(a[kf], b, c);
            }
            acc[nt] = c;
        }
        float s[4] = {0.f, 0.f, 0.f, 0.f};
        #pragma unroll
        for (int nt = 0; nt < 8; ++nt) {
            float bv = bc[nt * 16 + l15], cv = bc[128 + nt * 16 + l15];
            #pragma unroll
            for (int i = 0; i < 4; ++i)
                s[i] += ftanh(acc[nt][i] + bv) * cv;
        }
        #pragma unroll
        for (int i = 0; i < 4; ++i) {
            s[i] += __shfl_xor(s[i], 1);
            s[i] += __shfl_xor(s[i], 2);
            s[i] += __shfl_xor(s[i], 4);
            s[i] += __shfl_xor(s[i], 8);
        }
        if (l15 == 0) {
            #pragma unroll
            for (int i = 0; i < 4; ++i) sc_lds[wave * 16 + l4 * 4 + i] = s[i];
        }
    }
    __syncthreads();
    if (tid < 32) {
        int ml = slens[tid];
        for (int off = 16; off; off >>= 1) ml = max(ml, __shfl_xor(ml, off, 32));
        bool v = tid < ml;
        float sc = v ? sc_lds[tid] : -1e30f;
        float mx = sc;
        for (int off = 16; off; off >>= 1) mx = fmaxf(mx, __shfl_xor(mx, off, 32));
        float e = v ? __expf(sc - mx) : 0.f;
        float sum = e;
        for (int off = 16; off; off >>= 1) sum += __shfl_xor(sum, off, 32);
        p_lds[tid] = e / fmaxf(sum, 1e-30f);
    }
    __syncthreads();
    float acc2 = 0.f;
    for (int t = 0; t < 32; ++t) acc2 += p_lds[t] * bf2f(tile[t * SP + tid]);
    dv[tid] = acc2;
    __syncthreads();
    int c = tid >> 5, q0 = (tid & 31) * 8;
    float partial = 0.f;
    #pragma unroll
    for (int q = 0; q < 8; ++q)
        partial += dv[q0 + q] * bf2f(fcW[(size_t)c * 256 + q0 + q]);
    for (int off = 16; off; off >>= 1) partial += __shfl_xor(partial, off, 32);
    if ((tid & 31) == 0) {
        float v = partial + bf2f(fcb[c]);
        if (*flagp) ((float*)outp)[g * 8 + c] = v;
        else        ((ushort_t*)outp)[g * 8 + c] = f2bf(v);
    }
}

// ---------------------------------------------------------------------------
extern "C" void kernel_launch(void* const* d_in, const int* in_sizes, int n_in,
                              void* d_out, int out_size, void* d_ws, size_t ws_size,
                              hipStream_t stream) {
    const int* x = (const int*)d_in[0];
    char* ws = (char*)d_ws;

    const size_t O_CONV = 0;            // canonical bf16 inputs (~14 MB)
    const size_t O_WOUT = 14680064;     // [65536,256] bf16  33.55 MB
    const size_t O_SENT = 48234496;     // [1024,256] bf16
    const size_t O_SOUT = 48758784;     // [1024,256] bf16
    const size_t O_SPTF = 49283072;     // spT fwd [2*32*96*64] bf16 1.5MB
    const size_t O_SPTB = 50855936;     // spT bwd
    const size_t O_LENS = 52428800;     // wlens [1024] int
    const size_t O_SLEN = 52432896;     // slens [32] int
    const size_t O_DMAX = 52433024;     // per-doc word-len maxima [32] int
    const size_t O_FLAG = 52433152;

    ushort_t* conv = (ushort_t*)(ws + O_CONV);
    ushort_t* wout = (ushort_t*)(ws + O_WOUT);
    ushort_t* sent = (ushort_t*)(ws + O_SENT);
    ushort_t* sout = (ushort_t*)(ws + O_SOUT);
    ushort_t* sptf = (ushort_t*)(ws + O_SPTF);
    ushort_t* sptb = (ushort_t*)(ws + O_SPTB);
    int* wlens = (int*)(ws + O_LENS);
    int* slens = (int*)(ws + O_SLEN);
    int* dmax  = (int*)(ws + O_DMAX);
    int* flag  = (int*)(ws + O_FLAG);

    ConvArgs ca;
    ushort_t* cw[25];
    int off = 0, blk = 0;
    for (int i = 1; i <= 25; ++i) {
        int j = i - 1;
        int cnt = in_sizes[i];
        ca.src[j] = d_in[i];
        ca.dstoff[j] = off;
        ca.count[j] = cnt;
        ca.cumblk[j] = blk;
        cw[j] = conv + off;
        off += cnt;
        blk += (cnt + 2047) / 2048;
    }
    ca.cumblk[25] = blk;

    // 1) lengths + dtype detect (33 blocks)
    lens_kernel<<<33, 64, 0, stream>>>(x, (const unsigned int*)d_in[1],
                                       wlens, slens, dmax, flag);
    // 2) canonicalize float inputs -> bf16
    convert_kernel<<<blk, 256, 0, stream>>>(ca, conv, flag);
    // 3) word BiGRU (register x-fragments, true LDS-only barrier)
    word_gru_kernel<<<dim3(64, 2), 512, 0, stream>>>(
        x, cw[0],
        cw[1], cw[2], cw[3], cw[4],      // wf: Wih, Whh, bih, bhh
        cw[5], cw[6], cw[7], cw[8],      // wb
        wlens, wout);
    // 4) word attention fused -> sent
    word_attn_kernel<<<1024, 256, 0, stream>>>(wout, cw[17], cw[18], cw[19], dmax, sent);
    // 5) sentence xp -> transposed spT (both dirs)
    spt_gemm_kernel<<<dim3(16, 12), 256, 0, stream>>>(sent, cw[9], cw[11], sptf,
                                                      cw[13], cw[15], sptb);
    // 6) sentence BiGRU (lean: h-only MFMAs, register xp prefetch)
    sent_gru_kernel<<<dim3(2, 2), 512, 0, stream>>>(
        sptf, sptb, cw[10], cw[14], cw[12], cw[16], slens, sout);
    // 7) sentence attention + FC -> d_out
    sent_attn_fc_kernel<<<32, 256, 0, stream>>>(sout, cw[20], cw[21], cw[22],
                                                cw[23], cw[24], slens, flag, d_out);
    (void)n_in; (void)out_size; (void)ws_size;
}

// Round 10
// 285.743 us; speedup vs baseline: 1.1158x; 1.1086x over previous
//
#include <hip/hip_runtime.h>
#include <hip/hip_bf16.h>

typedef unsigned short ushort_t;
typedef __attribute__((ext_vector_type(4))) float floatx4;
typedef __attribute__((ext_vector_type(8))) short short8;

#define L2E 1.4426950408889634f

__device__ __forceinline__ float bf2f(ushort_t u) {
    union { unsigned int i; float f; } v; v.i = ((unsigned int)u) << 16; return v.f;
}
__device__ __forceinline__ ushort_t f2bf(float f) {
    union { float f; unsigned int i; } v; v.f = f;
    unsigned int i = v.i;
    i += 0x7fffu + ((i >> 16) & 1u);            // RNE
    return (ushort_t)(i >> 16);
}
__device__ __forceinline__ float fexp2(float x) {
#if __has_builtin(__builtin_amdgcn_exp2f)
    return __builtin_amdgcn_exp2f(x);
#else
    return __expf(x * 0.6931471805599453f);
#endif
}
__device__ __forceinline__ float frcp(float x) {
#if __has_builtin(__builtin_amdgcn_rcpf)
    return __builtin_amdgcn_rcpf(x);
#else
    return 1.f / x;
#endif
}
// σ(x) with pre-scaled input a = −log2e·x ; tanh(x) with y = 2·log2e·x.
__device__ __forceinline__ float sig2(float a)  { return frcp(1.f + fexp2(a)); }
__device__ __forceinline__ float tanh2(float y) { return 1.f - 2.f * frcp(1.f + fexp2(y)); }

__device__ __forceinline__ unsigned int packbf(float a, float b) {
    float2 t; t.x = a; t.y = b;
    __hip_bfloat162 h = __float22bfloat162_rn(t);
    union { __hip_bfloat162 h; unsigned int u; } v; v.h = h; return v.u;
}

__device__ __forceinline__ floatx4 MFMA16(short8 a, short8 b, floatx4 c) {
    return __builtin_amdgcn_mfma_f32_16x16x32_bf16(a, b, c, 0, 0, 0);
}

// LDS-only barrier: lgkmcnt(0) only (vmcnt/expcnt maxed) + raw s_barrier.
__device__ __forceinline__ void bar_lds() {
    __builtin_amdgcn_s_waitcnt(0xc07f);
    __builtin_amdgcn_s_barrier();
}

// Swizzled LDS index for [chunk c][seq m][8 elems] bf16 tiles.
#define XIDX(c, m) ((((c) * 16) + ((m) ^ ((c) & 15))) * 8)

// ---------------------------------------------------------------------------
// K1: lengths + dtype detect.
// ---------------------------------------------------------------------------
__global__ __launch_bounds__(64) void lens_kernel(const int* __restrict__ x,
                                                  const unsigned int* __restrict__ raw,
                                                  int* wlens, int* slens, int* dmax,
                                                  int* flag) {
    int b = blockIdx.x, s = threadIdx.x;
    if (b == 32) {
        int c = 0;
        for (int i = 0; i < 16; ++i) {
            unsigned int v = raw[s * 16 + i];
            unsigned int e = (v >> 7) & 0xFFu;
            if (e > 0x7Bu) ++c;
        }
        c += __shfl_xor(c, 1);  c += __shfl_xor(c, 2);  c += __shfl_xor(c, 4);
        c += __shfl_xor(c, 8);  c += __shfl_xor(c, 16); c += __shfl_xor(c, 32);
        if (s == 0) *flag = (c > 64) ? 1 : 0;    // 1 => inputs are f32
        return;
    }
    int last = 0;
    if (s < 32) {
        const int* tok = x + (b * 32 + s) * 64;
        for (int t = 0; t < 64; t += 4) {
            int4 v = *(const int4*)(tok + t);
            if (v.x) last = t + 1;
            if (v.y) last = t + 2;
            if (v.z) last = t + 3;
            if (v.w) last = t + 4;
        }
        wlens[b * 32 + s] = last ? last : 1;
    }
    int len = (s < 32) ? (last ? last : 1) : 0;
    int lm = len;
    for (int off = 32; off; off >>= 1) lm = max(lm, __shfl_xor(lm, off));
    unsigned long long mask = __ballot(s < 32 && last > 0);
    if (s == 0) {
        slens[b] = mask ? (63 - (int)__clzll(mask) + 1) : 1;
        dmax[b] = lm;
    }
}

// ---------------------------------------------------------------------------
// K0b: canonicalize float inputs -> bf16, folding activation scale factors
// into GRU / attn-proj weights: r,z rows × (−log2e); n rows × (2·log2e);
// attn proj W,b × (2·log2e). Gate math then uses raw v_exp/v_rcp only.
// ---------------------------------------------------------------------------
struct ConvArgs {
    const void* src[25];
    int dstoff[25];
    int count[25];
    int cumblk[26];
    int mode[25];     // 0 none, 1 GRU (row<256 ? -L2E : 2L2E), 2 all 2L2E
    int rowdiv[25];
};

__global__ __launch_bounds__(256) void convert_kernel(ConvArgs a, ushort_t* __restrict__ dst,
                                                      const int* __restrict__ flag) {
    int b = blockIdx.x;
    int lo = 0, hi = 24;
    while (lo < hi) { int mid = (lo + hi + 1) >> 1; if (a.cumblk[mid] <= b) lo = mid; else hi = mid - 1; }
    int j = lo;
    int base = (b - a.cumblk[j]) * 2048 + threadIdx.x * 8;
    if (base >= a.count[j]) return;
    ushort_t* out = dst + a.dstoff[j] + base;
    int m = a.mode[j], rd = a.rowdiv[j];
    float f[8];
    if (*flag) {
        const float* s = (const float*)a.src[j] + base;
        float4 v0 = *(const float4*)s;
        float4 v1 = *(const float4*)(s + 4);
        f[0] = v0.x; f[1] = v0.y; f[2] = v0.z; f[3] = v0.w;
        f[4] = v1.x; f[5] = v1.y; f[6] = v1.z; f[7] = v1.w;
    } else {
        const ushort_t* s = (const ushort_t*)a.src[j] + base;
        uint4 v = *(const uint4*)s;
        const ushort_t* u = (const ushort_t*)&v;
        #pragma unroll
        for (int e = 0; e < 8; ++e) f[e] = bf2f(u[e]);
    }
    union { ushort_t u[8]; uint4 v; } o;
    #pragma unroll
    for (int e = 0; e < 8; ++e) {
        float sc = 1.f;
        if (m == 2) sc = 2.f * L2E;
        else if (m == 1) sc = ((base + e) / rd < 256) ? -L2E : 2.f * L2E;
        o.u[e] = f2bf(f[e] * sc);
    }
    *(uint4*)out = o.v;
}

// ---------------------------------------------------------------------------
// Word-level BiGRU: fused gather+proj+recurrence, in-register gates.
// grid (64, 2); 512 thr. x B-frags loaded directly from emb into registers.
// Gate math: raw v_exp2/v_rcp (scales folded into weights at convert).
// ---------------------------------------------------------------------------
__global__ __launch_bounds__(512, 2) void word_gru_kernel(
        const int* __restrict__ x, const ushort_t* __restrict__ emb,
        const ushort_t* __restrict__ Wih_f, const ushort_t* __restrict__ Whh_f,
        const ushort_t* __restrict__ bih_f, const ushort_t* __restrict__ bhh_f,
        const ushort_t* __restrict__ Wih_b, const ushort_t* __restrict__ Whh_b,
        const ushort_t* __restrict__ bih_b, const ushort_t* __restrict__ bhh_b,
        const int* __restrict__ lens, ushort_t* __restrict__ out) {
    const int T = 64;
    __shared__ ushort_t h_buf[2][2048];
    __shared__ float bsum_lds[256];
    __shared__ float bihn_lds[128];
    __shared__ float bhhn_lds[128];
    __shared__ int tok_lds[1024];            // [t][s]

    int tid = threadIdx.x;
    int d = blockIdx.y;
    int n0 = blockIdx.x * 16;
    const ushort_t* Wih = d ? Wih_b : Wih_f;
    const ushort_t* Whh = d ? Whh_b : Whh_f;
    const ushort_t* bih = d ? bih_b : bih_f;
    const ushort_t* bhh = d ? bhh_b : bhh_f;
    int lane = tid & 63, wave = tid >> 6;
    int l15 = lane & 15, l4 = (lane >> 4) & 3;
    int jt = wave * 16;
    int j0 = jt + l4 * 4;

    for (int i = tid; i < 1024; i += 512) {
        int t = i >> 4, s = i & 15;
        tok_lds[i] = x[(n0 + s) * 64 + t];
    }
    if (tid < 256) bsum_lds[tid] = bf2f(bih[tid]) + bf2f(bhh[tid]);
    else if (tid < 384) {
        bihn_lds[tid - 256] = bf2f(bih[tid]);
        bhhn_lds[tid - 256] = bf2f(bhh[tid]);
    }
    { uint2 z = {0u, 0u}; *(uint2*)&h_buf[0][tid * 4] = z; }

    short8 wr[4], wz[4], wn[4], ur[4], uz[4], un[4];
    #pragma unroll
    for (int kf = 0; kf < 4; ++kf) {
        int col = kf * 32 + l4 * 8;
        wr[kf] = *(const short8*)(Wih + (size_t)(jt + l15) * 128 + col);
        wz[kf] = *(const short8*)(Wih + (size_t)(128 + jt + l15) * 128 + col);
        wn[kf] = *(const short8*)(Wih + (size_t)(256 + jt + l15) * 128 + col);
        ur[kf] = *(const short8*)(Whh + (size_t)(jt + l15) * 128 + col);
        uz[kf] = *(const short8*)(Whh + (size_t)(128 + jt + l15) * 128 + col);
        un[kf] = *(const short8*)(Whh + (size_t)(256 + jt + l15) * 128 + col);
    }
    __syncthreads();

    floatx4 br  = *(floatx4*)&bsum_lds[j0];
    floatx4 bz  = *(floatx4*)&bsum_lds[128 + j0];
    floatx4 bxn = *(floatx4*)&bihn_lds[j0];
    floatx4 bhn = *(floatx4*)&bhhn_lds[j0];
    int lv = lens[n0 + l15];
    float hreg[4] = {0.f, 0.f, 0.f, 0.f};

    short8 xc[4], xn_[4];
    {
        int t0 = d ? (T - 1) : 0;
        size_t rb = (size_t)tok_lds[t0 * 16 + l15] * 128 + l4 * 8;
        #pragma unroll
        for (int kf = 0; kf < 4; ++kf)
            xc[kf] = *(const short8*)(emb + rb + kf * 32);
    }

    for (int ti = 0; ti < T; ++ti) {
        int t = d ? (T - 1 - ti) : ti;
        bool have_next = (ti + 1) < T;
        if (have_next) {
            int tn = d ? (T - 2 - ti) : (ti + 1);
            size_t rb = (size_t)tok_lds[tn * 16 + l15] * 128 + l4 * 8;
            #pragma unroll
            for (int kf = 0; kf < 4; ++kf)
                xn_[kf] = *(const short8*)(emb + rb + kf * 32);
        }
        short8 hb[4];
        #pragma unroll
        for (int kf = 0; kf < 4; ++kf)
            hb[kf] = *(const short8*)&h_buf[ti & 1][XIDX(kf * 4 + l4, l15)];
        floatx4 arx = br, azx = bz, axn = bxn;
        floatx4 arh = {0.f, 0.f, 0.f, 0.f}, azh = {0.f, 0.f, 0.f, 0.f}, ahn = bhn;
        #pragma unroll
        for (int kf = 0; kf < 4; ++kf) {
            arx = MFMA16(wr[kf], xc[kf], arx);
            azx = MFMA16(wz[kf], xc[kf], azx);
            axn = MFMA16(wn[kf], xc[kf], axn);
        }
        #pragma unroll
        for (int kf = 0; kf < 4; ++kf) {
            arh = MFMA16(ur[kf], hb[kf], arh);
            azh = MFMA16(uz[kf], hb[kf], azh);
            ahn = MFMA16(un[kf], hb[kf], ahn);
        }
        bool valid = t < lv;
        float hnew[4];
        #pragma unroll
        for (int i = 0; i < 4; ++i) {
            float r  = sig2(arx[i] + arh[i]);
            float z  = sig2(azx[i] + azh[i]);
            float nn = tanh2(axn[i] + r * ahn[i]);
            hnew[i] = valid ? (nn + z * (hreg[i] - nn)) : hreg[i];
            hreg[i] = hnew[i];
        }
        uint2 h2, o2;
        h2.x = packbf(hnew[0], hnew[1]);
        h2.y = packbf(hnew[2], hnew[3]);
        o2.x = valid ? h2.x : 0u;
        o2.y = valid ? h2.y : 0u;
        *(uint2*)&h_buf[(ti & 1) ^ 1][XIDX(j0 >> 3, l15) + (j0 & 7)] = h2;
        *(uint2*)(out + ((size_t)(n0 + l15) * T + t) * 256 + d * 128 + j0) = o2;
        if (have_next) {
            #pragma unroll
            for (int kf = 0; kf < 4; ++kf) xc[kf] = xn_[kf];
        }
        bar_lds();
    }
}

// ---------------------------------------------------------------------------
// Sentence xp GEMM -> transposed layout spT (weights pre-scaled at convert).
// ---------------------------------------------------------------------------
__global__ __launch_bounds__(256) void spt_gemm_kernel(const ushort_t* __restrict__ A,
                                                       const ushort_t* __restrict__ Bf_,
                                                       const ushort_t* __restrict__ biasf,
                                                       ushort_t* __restrict__ Tf_,
                                                       const ushort_t* __restrict__ Bb_,
                                                       const ushort_t* __restrict__ biasb,
                                                       ushort_t* __restrict__ Tb_) {
    __shared__ ushort_t As[64 * 256];
    __shared__ ushort_t Bs[64 * 256];
    const int K = 256;
    int tid = threadIdx.x;
    int by = blockIdx.y;
    bool sb = by >= 6;
    int n0 = (sb ? by - 6 : by) * 64;
    const ushort_t* B = sb ? Bb_ : Bf_;
    const ushort_t* bias = sb ? biasb : biasf;
    ushort_t* Tp = sb ? Tb_ : Tf_;
    int m0 = blockIdx.x * 64;
    for (int idx = tid; idx < 2048; idx += 256) {
        int m = idx & 63, c = idx >> 6;
        *(uint4*)&As[(c * 64 + m) * 8] = *(const uint4*)(A + (size_t)(m0 + m) * K + c * 8);
    }
    for (int idx = tid; idx < 2048; idx += 256) {
        int n = idx & 63, c = idx >> 6;
        *(uint4*)&Bs[(c * 64 + n) * 8] = *(const uint4*)(B + (size_t)(n0 + n) * K + c * 8);
    }
    __syncthreads();
    int lane = tid & 63, wave = tid >> 6;
    int wm = (wave & 1) * 32, wn = (wave >> 1) * 32;
    int l15 = lane & 15, l4 = lane >> 4;
    floatx4 acc[2][2] = {};
    for (int kf = 0; kf < 8; ++kf) {
        int c = kf * 4 + l4;
        short8 a0 = *(const short8*)&As[(c * 64 + wm + l15) * 8];
        short8 a1 = *(const short8*)&As[(c * 64 + wm + 16 + l15) * 8];
        short8 b0 = *(const short8*)&Bs[(c * 64 + wn + l15) * 8];
        short8 b1 = *(const short8*)&Bs[(c * 64 + wn + 16 + l15) * 8];
        acc[0][0] = MFMA16(a0, b0, acc[0][0]);
        acc[0][1] = MFMA16(a0, b1, acc[0][1]);
        acc[1][0] = MFMA16(a1, b0, acc[1][0]);
        acc[1][1] = MFMA16(a1, b1, acc[1][1]);
    }
    for (int nt = 0; nt < 2; ++nt) {
        int n = n0 + wn + nt * 16 + l15;
        float bv = bf2f(bias[n]);
        int jc = n >> 2, ji = n & 3;
        for (int mt = 0; mt < 2; ++mt) {
            int mbase = m0 + wm + mt * 16 + l4 * 4;
            #pragma unroll
            for (int i = 0; i < 4; ++i) {
                int m = mbase + i;
                int doc = m >> 5, t = m & 31;
                size_t dst = ((size_t)((doc >> 4) * 32 + t) * 96 + jc) * 64
                           + (doc & 15) * 4 + ji;
                Tp[dst] = f2bf(acc[mt][nt][i] + bv);
            }
        }
    }
}

// ---------------------------------------------------------------------------
// Sentence-level BiGRU (lean): h-only MFMAs; xp from spT (scaled).
// ---------------------------------------------------------------------------
__global__ __launch_bounds__(512, 1) void sent_gru_kernel(
        const ushort_t* __restrict__ spT_f, const ushort_t* __restrict__ spT_b,
        const ushort_t* __restrict__ Whh_f, const ushort_t* __restrict__ Whh_b,
        const ushort_t* __restrict__ bhh_f, const ushort_t* __restrict__ bhh_b,
        const int* __restrict__ lens, ushort_t* __restrict__ out) {
    const int T = 32;
    __shared__ ushort_t h_buf[2][2048];
    __shared__ float bhh_lds[384];

    int tid = threadIdx.x;
    int d = blockIdx.y;
    int n0 = blockIdx.x * 16;
    const ushort_t* spT = d ? spT_b : spT_f;
    const ushort_t* Whh = d ? Whh_b : Whh_f;
    const ushort_t* bhh = d ? bhh_b : bhh_f;
    int lane = tid & 63, wave = tid >> 6;
    int l15 = lane & 15, l4 = (lane >> 4) & 3;
    int jt = wave * 16;
    int j0 = jt + l4 * 4;
    int jc = j0 >> 2;

    if (tid < 384) bhh_lds[tid] = bf2f(bhh[tid]);
    { uint2 z = {0u, 0u}; *(uint2*)&h_buf[0][tid * 4] = z; }

    short8 ur[4], uz[4], un[4];
    #pragma unroll
    for (int kf = 0; kf < 4; ++kf) {
        int col = kf * 32 + l4 * 8;
        ur[kf] = *(const short8*)(Whh + (size_t)(jt + l15) * 128 + col);
        uz[kf] = *(const short8*)(Whh + (size_t)(128 + jt + l15) * 128 + col);
        un[kf] = *(const short8*)(Whh + (size_t)(256 + jt + l15) * 128 + col);
    }
    __syncthreads();

    floatx4 br  = *(floatx4*)&bhh_lds[j0];
    floatx4 bz  = *(floatx4*)&bhh_lds[128 + j0];
    floatx4 bhn = *(floatx4*)&bhh_lds[256 + j0];
    int lv = lens[n0 + l15];
    float hreg[4] = {0.f, 0.f, 0.f, 0.f};

    const ushort_t* sp = spT + (size_t)(blockIdx.x * 32) * 96 * 64 + l15 * 4;
    ushort4 xr_c, xz_c, xn_c, xr_n, xz_n, xn_n;
    {
        int t0 = d ? (T - 1) : 0;
        size_t rb = (size_t)t0 * 96 * 64;
        xr_c = *(const ushort4*)(sp + rb + (size_t)jc * 64);
        xz_c = *(const ushort4*)(sp + rb + (size_t)(32 + jc) * 64);
        xn_c = *(const ushort4*)(sp + rb + (size_t)(64 + jc) * 64);
    }

    for (int ti = 0; ti < T; ++ti) {
        int t = d ? (T - 1 - ti) : ti;
        int cur = ti & 1;
        bool have_next = (ti + 1) < T;
        if (have_next) {
            int tn = d ? (T - 2 - ti) : (ti + 1);
            size_t rb = (size_t)tn * 96 * 64;
            xr_n = *(const ushort4*)(sp + rb + (size_t)jc * 64);
            xz_n = *(const ushort4*)(sp + rb + (size_t)(32 + jc) * 64);
            xn_n = *(const ushort4*)(sp + rb + (size_t)(64 + jc) * 64);
        }
        floatx4 ar = br, az = bz, ahn = bhn;
        #pragma unroll
        for (int kf = 0; kf < 4; ++kf) {
            short8 hb = *(const short8*)&h_buf[cur][XIDX(kf * 4 + l4, l15)];
            ar  = MFMA16(ur[kf], hb, ar);
            az  = MFMA16(uz[kf], hb, az);
            ahn = MFMA16(un[kf], hb, ahn);
        }
        float xr[4] = {bf2f(xr_c.x), bf2f(xr_c.y), bf2f(xr_c.z), bf2f(xr_c.w)};
        float xz[4] = {bf2f(xz_c.x), bf2f(xz_c.y), bf2f(xz_c.z), bf2f(xz_c.w)};
        float xn[4] = {bf2f(xn_c.x), bf2f(xn_c.y), bf2f(xn_c.z), bf2f(xn_c.w)};
        bool valid = t < lv;
        float hnew[4];
        #pragma unroll
        for (int i = 0; i < 4; ++i) {
            float r  = sig2(xr[i] + ar[i]);
            float z  = sig2(xz[i] + az[i]);
            float nn = tanh2(xn[i] + r * ahn[i]);
            hnew[i] = valid ? (nn + z * (hreg[i] - nn)) : hreg[i];
            hreg[i] = hnew[i];
        }
        uint2 h2, o2;
        h2.x = packbf(hnew[0], hnew[1]);
        h2.y = packbf(hnew[2], hnew[3]);
        o2.x = valid ? h2.x : 0u;
        o2.y = valid ? h2.y : 0u;
        *(uint2*)&h_buf[cur ^ 1][XIDX(j0 >> 3, l15) + (j0 & 7)] = h2;
        *(uint2*)(out + ((size_t)(n0 + l15) * T + t) * 256 + d * 128 + j0) = o2;
        if (have_next) { xr_c = xr_n; xz_c = xz_n; xn_c = xn_n; }
        bar_lds();
    }
}

// ---------------------------------------------------------------------------
// Word attention fused (proj W,b pre-scaled by 2·log2e).
// ---------------------------------------------------------------------------
#define SP 264
__global__ __launch_bounds__(256) void word_attn_kernel(const ushort_t* __restrict__ wout,
                                                        const ushort_t* __restrict__ W,
                                                        const ushort_t* __restrict__ bias,
                                                        const ushort_t* __restrict__ ctx,
                                                        const int* __restrict__ dmax,
                                                        ushort_t* __restrict__ sent) {
    __shared__ ushort_t tile[64 * SP];
    __shared__ float bc[256];
    __shared__ float sc_lds[64];
    __shared__ float p_lds[64];
    int tid = threadIdx.x, g = blockIdx.x;
    for (int idx = tid; idx < 2048; idx += 256) {
        int row = idx >> 5, k0 = (idx & 31) * 8;
        *(uint4*)&tile[row * SP + k0] = *(const uint4*)(wout + ((size_t)g * 64 + row) * 256 + k0);
    }
    if (tid < 128) bc[tid] = bf2f(bias[tid]);
    else bc[tid] = bf2f(ctx[tid - 128]);
    __syncthreads();
    int lane = tid & 63, wave = tid >> 6;
    int l15 = lane & 15, l4 = (lane >> 4) & 3;
    short8 a[8];
    #pragma unroll
    for (int kf = 0; kf < 8; ++kf)
        a[kf] = *(const short8*)&tile[(wave * 16 + l15) * SP + kf * 32 + l4 * 8];
    floatx4 acc[8];
    #pragma unroll
    for (int nt = 0; nt < 8; ++nt) {
        floatx4 c = {0.f, 0.f, 0.f, 0.f};
        #pragma unroll
        for (int kf = 0; kf < 8; ++kf) {
            short8 b = *(const short8*)(W + (size_t)(nt * 16 + l15) * 256 + kf * 32 + l4 * 8);
            c = MFMA16(a[kf], b, c);
        }
        acc[nt] = c;
    }
    float s[4] = {0.f, 0.f, 0.f, 0.f};
    #pragma unroll
    for (int nt = 0; nt < 8; ++nt) {
        float bv = bc[nt * 16 + l15], cv = bc[128 + nt * 16 + l15];
        #pragma unroll
        for (int i = 0; i < 4; ++i)
            s[i] += tanh2(acc[nt][i] + bv) * cv;
    }
    #pragma unroll
    for (int i = 0; i < 4; ++i) {
        s[i] += __shfl_xor(s[i], 1);
        s[i] += __shfl_xor(s[i], 2);
        s[i] += __shfl_xor(s[i], 4);
        s[i] += __shfl_xor(s[i], 8);
    }
    if (l15 == 0) {
        #pragma unroll
        for (int i = 0; i < 4; ++i) sc_lds[wave * 16 + l4 * 4 + i] = s[i];
    }
    __syncthreads();
    if (tid < 64) {
        int ml = dmax[tid & 31];
        for (int off = 32; off; off >>= 1) ml = max(ml, __shfl_xor(ml, off));
        bool v = tid < ml;
        float sc = v ? sc_lds[tid] : -1e30f;
        float mx = sc;
        for (int off = 32; off; off >>= 1) mx = fmaxf(mx, __shfl_xor(mx, off));
        float e = v ? __expf(sc - mx) : 0.f;
        float sum = e;
        for (int off = 32; off; off >>= 1) sum += __shfl_xor(sum, off);
        p_lds[tid] = e * frcp(fmaxf(sum, 1e-30f));
    }
    __syncthreads();
    float acc2 = 0.f;
    for (int t = 0; t < 64; ++t) acc2 += p_lds[t] * bf2f(tile[t * SP + tid]);
    sent[(size_t)g * 256 + tid] = f2bf(acc2);
}

// ---------------------------------------------------------------------------
// Sentence attention + FC fused (proj pre-scaled; FC unscaled).
// ---------------------------------------------------------------------------
__global__ __launch_bounds__(256) void sent_attn_fc_kernel(const ushort_t* __restrict__ sout,
                                                           const ushort_t* __restrict__ W,
                                                           const ushort_t* __restrict__ bias,
                                                           const ushort_t* __restrict__ ctx,
                                                           const ushort_t* __restrict__ fcW,
                                                           const ushort_t* __restrict__ fcb,
                                                           const int* __restrict__ slens,
                                                           const int* __restrict__ flagp,
                                                           void* __restrict__ outp) {
    __shared__ ushort_t tile[32 * SP];
    __shared__ float bc[256];
    __shared__ float sc_lds[32];
    __shared__ float p_lds[32];
    __shared__ float dv[256];
    int tid = threadIdx.x, g = blockIdx.x;
    for (int idx = tid; idx < 1024; idx += 256) {
        int row = idx >> 5, k0 = (idx & 31) * 8;
        *(uint4*)&tile[row * SP + k0] = *(const uint4*)(sout + ((size_t)g * 32 + row) * 256 + k0);
    }
    if (tid < 128) bc[tid] = bf2f(bias[tid]);
    else bc[tid] = bf2f(ctx[tid - 128]);
    __syncthreads();
    int lane = tid & 63, wave = tid >> 6;
    int l15 = lane & 15, l4 = (lane >> 4) & 3;
    if (wave < 2) {
        short8 a[8];
        #pragma unroll
        for (int kf = 0; kf < 8; ++kf)
            a[kf] = *(const short8*)&tile[(wave * 16 + l15) * SP + kf * 32 + l4 * 8];
        floatx4 acc[8];
        #pragma unroll
        for (int nt = 0; nt < 8; ++nt) {
            floatx4 c = {0.f, 0.f, 0.f, 0.f};
            #pragma unroll
            for (int kf = 0; kf < 8; ++kf) {
                short8 b = *(const short8*)(W + (size_t)(nt * 16 + l15) * 256 + kf * 32 + l4 * 8);
                c = MFMA16(a[kf], b, c);
            }
            acc[nt] = c;
        }
        float s[4] = {0.f, 0.f, 0.f, 0.f};
        #pragma unroll
        for (int nt = 0; nt < 8; ++nt) {
            float bv = bc[nt * 16 + l15], cv = bc[128 + nt * 16 + l15];
            #pragma unroll
            for (int i = 0; i < 4; ++i)
                s[i] += tanh2(acc[nt][i] + bv) * cv;
        }
        #pragma unroll
        for (int i = 0; i < 4; ++i) {
            s[i] += __shfl_xor(s[i], 1);
            s[i] += __shfl_xor(s[i], 2);
            s[i] += __shfl_xor(s[i], 4);
            s[i] += __shfl_xor(s[i], 8);
        }
        if (l15 == 0) {
            #pragma unroll
            for (int i = 0; i < 4; ++i) sc_lds[wave * 16 + l4 * 4 + i] = s[i];
        }
    }
    __syncthreads();
    if (tid < 32) {
        int ml = slens[tid];
        for (int off = 16; off; off >>= 1) ml = max(ml, __shfl_xor(ml, off, 32));
        bool v = tid < ml;
        float sc = v ? sc_lds[tid] : -1e30f;
        float mx = sc;
        for (int off = 16; off; off >>= 1) mx = fmaxf(mx, __shfl_xor(mx, off, 32));
        float e = v ? __expf(sc - mx) : 0.f;
        float sum = e;
        for (int off = 16; off; off >>= 1) sum += __shfl_xor(sum, off, 32);
        p_lds[tid] = e * frcp(fmaxf(sum, 1e-30f));
    }
    __syncthreads();
    float acc2 = 0.f;
    for (int t = 0; t < 32; ++t) acc2 += p_lds[t] * bf2f(tile[t * SP + tid]);
    dv[tid] = acc2;
    __syncthreads();
    int c = tid >> 5, q0 = (tid & 31) * 8;
    float partial = 0.f;
    #pragma unroll
    for (int q = 0; q < 8; ++q)
        partial += dv[q0 + q] * bf2f(fcW[(size_t)c * 256 + q0 + q]);
    for (int off = 16; off; off >>= 1) partial += __shfl_xor(partial, off, 32);
    if ((tid & 31) == 0) {
        float v = partial + bf2f(fcb[c]);
        if (*flagp) ((float*)outp)[g * 8 + c] = v;
        else        ((ushort_t*)outp)[g * 8 + c] = f2bf(v);
    }
}

// ---------------------------------------------------------------------------
extern "C" void kernel_launch(void* const* d_in, const int* in_sizes, int n_in,
                              void* d_out, int out_size, void* d_ws, size_t ws_size,
                              hipStream_t stream) {
    const int* x = (const int*)d_in[0];
    char* ws = (char*)d_ws;

    const size_t O_CONV = 0;            // canonical bf16 inputs (~14 MB)
    const size_t O_WOUT = 14680064;     // [65536,256] bf16  33.55 MB
    const size_t O_SENT = 48234496;     // [1024,256] bf16
    const size_t O_SOUT = 48758784;     // [1024,256] bf16
    const size_t O_SPTF = 49283072;     // spT fwd 1.5MB
    const size_t O_SPTB = 50855936;     // spT bwd
    const size_t O_LENS = 52428800;
    const size_t O_SLEN = 52432896;
    const size_t O_DMAX = 52433024;
    const size_t O_FLAG = 52433152;

    ushort_t* conv = (ushort_t*)(ws + O_CONV);
    ushort_t* wout = (ushort_t*)(ws + O_WOUT);
    ushort_t* sent = (ushort_t*)(ws + O_SENT);
    ushort_t* sout = (ushort_t*)(ws + O_SOUT);
    ushort_t* sptf = (ushort_t*)(ws + O_SPTF);
    ushort_t* sptb = (ushort_t*)(ws + O_SPTB);
    int* wlens = (int*)(ws + O_LENS);
    int* slens = (int*)(ws + O_SLEN);
    int* dmax  = (int*)(ws + O_DMAX);
    int* flag  = (int*)(ws + O_FLAG);

    // mode/rowdiv per float tensor (d_in[1..25] -> j=0..24):
    // j0 emb:0; j1-8 word GRU (Wih rd128, Whh rd128, biases rd1) mode1;
    // j9-16 sent GRU (Wih rd256, Whh rd128, biases rd1) mode1;
    // j17,18 wproj W,b:2; j19 wctx:0; j20,21 sproj:2; j22 sctx:0; j23,24 fc:0.
    static const int kMode[25]   = {0, 1,1,1,1, 1,1,1,1, 1,1,1,1, 1,1,1,1, 2,2,0, 2,2,0, 0,0};
    static const int kRowdiv[25] = {1, 128,128,1,1, 128,128,1,1, 256,128,1,1, 256,128,1,1,
                                    1,1,1, 1,1,1, 1,1};

    ConvArgs ca;
    ushort_t* cw[25];
    int off = 0, blk = 0;
    for (int i = 1; i <= 25; ++i) {
        int j = i - 1;
        int cnt = in_sizes[i];
        ca.src[j] = d_in[i];
        ca.dstoff[j] = off;
        ca.count[j] = cnt;
        ca.cumblk[j] = blk;
        ca.mode[j] = kMode[j];
        ca.rowdiv[j] = kRowdiv[j];
        cw[j] = conv + off;
        off += cnt;
        blk += (cnt + 2047) / 2048;
    }
    ca.cumblk[25] = blk;

    // 1) lengths + dtype detect
    lens_kernel<<<33, 64, 0, stream>>>(x, (const unsigned int*)d_in[1],
                                       wlens, slens, dmax, flag);
    // 2) canonicalize (+ fold activation scales into weights)
    convert_kernel<<<blk, 256, 0, stream>>>(ca, conv, flag);
    // 3) word BiGRU
    word_gru_kernel<<<dim3(64, 2), 512, 0, stream>>>(
        x, cw[0],
        cw[1], cw[2], cw[3], cw[4],
        cw[5], cw[6], cw[7], cw[8],
        wlens, wout);
    // 4) word attention -> sent
    word_attn_kernel<<<1024, 256, 0, stream>>>(wout, cw[17], cw[18], cw[19], dmax, sent);
    // 5) sentence xp -> spT
    spt_gemm_kernel<<<dim3(16, 12), 256, 0, stream>>>(sent, cw[9], cw[11], sptf,
                                                      cw[13], cw[15], sptb);
    // 6) sentence BiGRU
    sent_gru_kernel<<<dim3(2, 2), 512, 0, stream>>>(
        sptf, sptb, cw[10], cw[14], cw[12], cw[16], slens, sout);
    // 7) sentence attention + FC -> d_out
    sent_attn_fc_kernel<<<32, 256, 0, stream>>>(sout, cw[20], cw[21], cw[22],
                                                cw[23], cw[24], slens, flag, d_out);
    (void)n_in; (void)out_size; (void)ws_size;
}

// Round 11
// 278.948 us; speedup vs baseline: 1.1430x; 1.0244x over previous
//
#include <hip/hip_runtime.h>
#include <hip/hip_bf16.h>

typedef unsigned short ushort_t;
typedef __attribute__((ext_vector_type(4))) float floatx4;
typedef __attribute__((ext_vector_type(8))) short short8;

#define L2E 1.4426950408889634f

__device__ __forceinline__ float bf2f(ushort_t u) {
    union { unsigned int i; float f; } v; v.i = ((unsigned int)u) << 16; return v.f;
}
__device__ __forceinline__ ushort_t f2bf(float f) {
    union { float f; unsigned int i; } v; v.f = f;
    unsigned int i = v.i;
    i += 0x7fffu + ((i >> 16) & 1u);            // RNE
    return (ushort_t)(i >> 16);
}
__device__ __forceinline__ float fexp2(float x) {
#if __has_builtin(__builtin_amdgcn_exp2f)
    return __builtin_amdgcn_exp2f(x);
#else
    return __expf(x * 0.6931471805599453f);
#endif
}
__device__ __forceinline__ float frcp(float x) {
#if __has_builtin(__builtin_amdgcn_rcpf)
    return __builtin_amdgcn_rcpf(x);
#else
    return 1.f / x;
#endif
}
// σ(x) with pre-scaled input a = −log2e·x ; tanh(x) with y = 2·log2e·x.
__device__ __forceinline__ float sig2(float a)  { return frcp(1.f + fexp2(a)); }
__device__ __forceinline__ float tanh2(float y) { return 1.f - 2.f * frcp(1.f + fexp2(y)); }

__device__ __forceinline__ unsigned int packbf(float a, float b) {
    float2 t; t.x = a; t.y = b;
    __hip_bfloat162 h = __float22bfloat162_rn(t);
    union { __hip_bfloat162 h; unsigned int u; } v; v.h = h; return v.u;
}

__device__ __forceinline__ floatx4 MFMA16(short8 a, short8 b, floatx4 c) {
    return __builtin_amdgcn_mfma_f32_16x16x32_bf16(a, b, c, 0, 0, 0);
}

// LDS-only barrier: lgkmcnt(0) only (vmcnt/expcnt maxed) + raw s_barrier.
__device__ __forceinline__ void bar_lds() {
    __builtin_amdgcn_s_waitcnt(0xc07f);
    __builtin_amdgcn_s_barrier();
}

// Swizzled LDS index for [chunk c][seq m(16)][8 elems] bf16 tiles.
#define XIDX(c, m) ((((c) * 16) + ((m) ^ ((c) & 15))) * 8)
// 8-seq variant: [chunk c(16)][seq m(8)][8 elems]
#define X8(c, m) ((((c) * 8) + ((m) ^ ((c) & 7))) * 8)

// ---------------------------------------------------------------------------
// K1: lengths + dtype detect.
// ---------------------------------------------------------------------------
__global__ __launch_bounds__(64) void lens_kernel(const int* __restrict__ x,
                                                  const unsigned int* __restrict__ raw,
                                                  int* wlens, int* slens, int* dmax,
                                                  int* flag) {
    int b = blockIdx.x, s = threadIdx.x;
    if (b == 32) {
        int c = 0;
        for (int i = 0; i < 16; ++i) {
            unsigned int v = raw[s * 16 + i];
            unsigned int e = (v >> 7) & 0xFFu;
            if (e > 0x7Bu) ++c;
        }
        c += __shfl_xor(c, 1);  c += __shfl_xor(c, 2);  c += __shfl_xor(c, 4);
        c += __shfl_xor(c, 8);  c += __shfl_xor(c, 16); c += __shfl_xor(c, 32);
        if (s == 0) *flag = (c > 64) ? 1 : 0;    // 1 => inputs are f32
        return;
    }
    int last = 0;
    if (s < 32) {
        const int* tok = x + (b * 32 + s) * 64;
        for (int t = 0; t < 64; t += 4) {
            int4 v = *(const int4*)(tok + t);
            if (v.x) last = t + 1;
            if (v.y) last = t + 2;
            if (v.z) last = t + 3;
            if (v.w) last = t + 4;
        }
        wlens[b * 32 + s] = last ? last : 1;
    }
    int len = (s < 32) ? (last ? last : 1) : 0;
    int lm = len;
    for (int off = 32; off; off >>= 1) lm = max(lm, __shfl_xor(lm, off));
    unsigned long long mask = __ballot(s < 32 && last > 0);
    if (s == 0) {
        slens[b] = mask ? (63 - (int)__clzll(mask) + 1) : 1;
        dmax[b] = lm;
    }
}

// ---------------------------------------------------------------------------
// K0b: canonicalize float inputs -> bf16, folding activation scale factors.
// ---------------------------------------------------------------------------
struct ConvArgs {
    const void* src[25];
    int dstoff[25];
    int count[25];
    int cumblk[26];
    int mode[25];     // 0 none, 1 GRU (row<256 ? -L2E : 2L2E), 2 all 2L2E
    int rowdiv[25];
};

__global__ __launch_bounds__(256) void convert_kernel(ConvArgs a, ushort_t* __restrict__ dst,
                                                      const int* __restrict__ flag) {
    int b = blockIdx.x;
    int lo = 0, hi = 24;
    while (lo < hi) { int mid = (lo + hi + 1) >> 1; if (a.cumblk[mid] <= b) lo = mid; else hi = mid - 1; }
    int j = lo;
    int base = (b - a.cumblk[j]) * 2048 + threadIdx.x * 8;
    if (base >= a.count[j]) return;
    ushort_t* out = dst + a.dstoff[j] + base;
    int m = a.mode[j], rd = a.rowdiv[j];
    float f[8];
    if (*flag) {
        const float* s = (const float*)a.src[j] + base;
        float4 v0 = *(const float4*)s;
        float4 v1 = *(const float4*)(s + 4);
        f[0] = v0.x; f[1] = v0.y; f[2] = v0.z; f[3] = v0.w;
        f[4] = v1.x; f[5] = v1.y; f[6] = v1.z; f[7] = v1.w;
    } else {
        const ushort_t* s = (const ushort_t*)a.src[j] + base;
        uint4 v = *(const uint4*)s;
        const ushort_t* u = (const ushort_t*)&v;
        #pragma unroll
        for (int e = 0; e < 8; ++e) f[e] = bf2f(u[e]);
    }
    union { ushort_t u[8]; uint4 v; } o;
    #pragma unroll
    for (int e = 0; e < 8; ++e) {
        float sc = 1.f;
        if (m == 2) sc = 2.f * L2E;
        else if (m == 1) sc = ((base + e) / rd < 256) ? -L2E : 2.f * L2E;
        o.u[e] = f2bf(f[e] * sc);
    }
    *(uint4*)out = o.v;
}

// ---------------------------------------------------------------------------
// Word-level BiGRU v5: 8 seqs/block, grid (128,2) = 256 blocks (all CUs).
// 512 thr / 8 waves; j-slice 16 per wave. B-frag cols 8 of 16 used (lanes
// l15>=8 duplicate col l15&7; writes guarded). Halves x/h read redundancy.
// ---------------------------------------------------------------------------
__global__ __launch_bounds__(512, 2) void word_gru_kernel(
        const int* __restrict__ x, const ushort_t* __restrict__ emb,
        const ushort_t* __restrict__ Wih_f, const ushort_t* __restrict__ Whh_f,
        const ushort_t* __restrict__ bih_f, const ushort_t* __restrict__ bhh_f,
        const ushort_t* __restrict__ Wih_b, const ushort_t* __restrict__ Whh_b,
        const ushort_t* __restrict__ bih_b, const ushort_t* __restrict__ bhh_b,
        const int* __restrict__ lens, ushort_t* __restrict__ out) {
    const int T = 64;
    __shared__ ushort_t h_buf[2][1024];      // [chunk16][seq8][8] swizzled
    __shared__ float bsum_lds[256];
    __shared__ float bihn_lds[128];
    __shared__ float bhhn_lds[128];
    __shared__ int tok_lds[512];             // [t][s(8)]

    int tid = threadIdx.x;
    int d = blockIdx.y;
    int n0 = blockIdx.x * 8;
    const ushort_t* Wih = d ? Wih_b : Wih_f;
    const ushort_t* Whh = d ? Whh_b : Whh_f;
    const ushort_t* bih = d ? bih_b : bih_f;
    const ushort_t* bhh = d ? bhh_b : bhh_f;
    int lane = tid & 63, wave = tid >> 6;
    int l15 = lane & 15, l4 = (lane >> 4) & 3;
    int s8 = l15 & 7;                        // clamped seq index
    bool sv = l15 < 8;                       // this lane's col is valid
    int jt = wave * 16;
    int j0 = jt + l4 * 4;

    {
        int t = tid >> 3, s = tid & 7;
        tok_lds[tid] = x[(n0 + s) * 64 + t];
    }
    if (tid < 256) bsum_lds[tid] = bf2f(bih[tid]) + bf2f(bhh[tid]);
    else if (tid < 384) {
        bihn_lds[tid - 256] = bf2f(bih[tid]);
        bhhn_lds[tid - 256] = bf2f(bhh[tid]);
    }
    if (tid < 256) { uint2 z = {0u, 0u}; *(uint2*)&h_buf[0][tid * 4] = z; }

    short8 wr[4], wz[4], wn[4], ur[4], uz[4], un[4];
    #pragma unroll
    for (int kf = 0; kf < 4; ++kf) {
        int col = kf * 32 + l4 * 8;
        wr[kf] = *(const short8*)(Wih + (size_t)(jt + l15) * 128 + col);
        wz[kf] = *(const short8*)(Wih + (size_t)(128 + jt + l15) * 128 + col);
        wn[kf] = *(const short8*)(Wih + (size_t)(256 + jt + l15) * 128 + col);
        ur[kf] = *(const short8*)(Whh + (size_t)(jt + l15) * 128 + col);
        uz[kf] = *(const short8*)(Whh + (size_t)(128 + jt + l15) * 128 + col);
        un[kf] = *(const short8*)(Whh + (size_t)(256 + jt + l15) * 128 + col);
    }
    __syncthreads();

    floatx4 br  = *(floatx4*)&bsum_lds[j0];
    floatx4 bz  = *(floatx4*)&bsum_lds[128 + j0];
    floatx4 bxn = *(floatx4*)&bihn_lds[j0];
    floatx4 bhn = *(floatx4*)&bhhn_lds[j0];
    int lv = lens[n0 + s8];
    float hreg[4] = {0.f, 0.f, 0.f, 0.f};

    short8 xc[4], xn_[4];
    {
        int t0 = d ? (T - 1) : 0;
        size_t rb = (size_t)tok_lds[t0 * 8 + s8] * 128 + l4 * 8;
        #pragma unroll
        for (int kf = 0; kf < 4; ++kf)
            xc[kf] = *(const short8*)(emb + rb + kf * 32);
    }

    for (int ti = 0; ti < T; ++ti) {
        int t = d ? (T - 1 - ti) : ti;
        bool have_next = (ti + 1) < T;
        if (have_next) {
            int tn = d ? (T - 2 - ti) : (ti + 1);
            size_t rb = (size_t)tok_lds[tn * 8 + s8] * 128 + l4 * 8;
            #pragma unroll
            for (int kf = 0; kf < 4; ++kf)
                xn_[kf] = *(const short8*)(emb + rb + kf * 32);
        }
        short8 hb[4];
        #pragma unroll
        for (int kf = 0; kf < 4; ++kf)
            hb[kf] = *(const short8*)&h_buf[ti & 1][X8(kf * 4 + l4, s8)];
        floatx4 arx = br, azx = bz, axn = bxn;
        floatx4 arh = {0.f, 0.f, 0.f, 0.f}, azh = {0.f, 0.f, 0.f, 0.f}, ahn = bhn;
        #pragma unroll
        for (int kf = 0; kf < 4; ++kf) {
            arx = MFMA16(wr[kf], xc[kf], arx);
            azx = MFMA16(wz[kf], xc[kf], azx);
            axn = MFMA16(wn[kf], xc[kf], axn);
        }
        #pragma unroll
        for (int kf = 0; kf < 4; ++kf) {
            arh = MFMA16(ur[kf], hb[kf], arh);
            azh = MFMA16(uz[kf], hb[kf], azh);
            ahn = MFMA16(un[kf], hb[kf], ahn);
        }
        bool valid = t < lv;
        float hnew[4];
        #pragma unroll
        for (int i = 0; i < 4; ++i) {
            float r  = sig2(arx[i] + arh[i]);
            float z  = sig2(azx[i] + azh[i]);
            float nn = tanh2(axn[i] + r * ahn[i]);
            hnew[i] = valid ? (nn + z * (hreg[i] - nn)) : hreg[i];
            hreg[i] = hnew[i];
        }
        if (sv) {
            uint2 h2, o2;
            h2.x = packbf(hnew[0], hnew[1]);
            h2.y = packbf(hnew[2], hnew[3]);
            o2.x = valid ? h2.x : 0u;
            o2.y = valid ? h2.y : 0u;
            *(uint2*)&h_buf[(ti & 1) ^ 1][X8(j0 >> 3, s8) + (j0 & 7)] = h2;
            *(uint2*)(out + ((size_t)(n0 + s8) * T + t) * 256 + d * 128 + j0) = o2;
        }
        if (have_next) {
            #pragma unroll
            for (int kf = 0; kf < 4; ++kf) xc[kf] = xn_[kf];
        }
        bar_lds();
    }
}

// ---------------------------------------------------------------------------
// Sentence xp GEMM -> transposed layout spT (weights pre-scaled at convert).
// ---------------------------------------------------------------------------
__global__ __launch_bounds__(256) void spt_gemm_kernel(const ushort_t* __restrict__ A,
                                                       const ushort_t* __restrict__ Bf_,
                                                       const ushort_t* __restrict__ biasf,
                                                       ushort_t* __restrict__ Tf_,
                                                       const ushort_t* __restrict__ Bb_,
                                                       const ushort_t* __restrict__ biasb,
                                                       ushort_t* __restrict__ Tb_) {
    __shared__ ushort_t As[64 * 256];
    __shared__ ushort_t Bs[64 * 256];
    const int K = 256;
    int tid = threadIdx.x;
    int by = blockIdx.y;
    bool sb = by >= 6;
    int n0 = (sb ? by - 6 : by) * 64;
    const ushort_t* B = sb ? Bb_ : Bf_;
    const ushort_t* bias = sb ? biasb : biasf;
    ushort_t* Tp = sb ? Tb_ : Tf_;
    int m0 = blockIdx.x * 64;
    for (int idx = tid; idx < 2048; idx += 256) {
        int m = idx & 63, c = idx >> 6;
        *(uint4*)&As[(c * 64 + m) * 8] = *(const uint4*)(A + (size_t)(m0 + m) * K + c * 8);
    }
    for (int idx = tid; idx < 2048; idx += 256) {
        int n = idx & 63, c = idx >> 6;
        *(uint4*)&Bs[(c * 64 + n) * 8] = *(const uint4*)(B + (size_t)(n0 + n) * K + c * 8);
    }
    __syncthreads();
    int lane = tid & 63, wave = tid >> 6;
    int wm = (wave & 1) * 32, wn = (wave >> 1) * 32;
    int l15 = lane & 15, l4 = lane >> 4;
    floatx4 acc[2][2] = {};
    for (int kf = 0; kf < 8; ++kf) {
        int c = kf * 4 + l4;
        short8 a0 = *(const short8*)&As[(c * 64 + wm + l15) * 8];
        short8 a1 = *(const short8*)&As[(c * 64 + wm + 16 + l15) * 8];
        short8 b0 = *(const short8*)&Bs[(c * 64 + wn + l15) * 8];
        short8 b1 = *(const short8*)&Bs[(c * 64 + wn + 16 + l15) * 8];
        acc[0][0] = MFMA16(a0, b0, acc[0][0]);
        acc[0][1] = MFMA16(a0, b1, acc[0][1]);
        acc[1][0] = MFMA16(a1, b0, acc[1][0]);
        acc[1][1] = MFMA16(a1, b1, acc[1][1]);
    }
    for (int nt = 0; nt < 2; ++nt) {
        int n = n0 + wn + nt * 16 + l15;
        float bv = bf2f(bias[n]);
        int jc = n >> 2, ji = n & 3;
        for (int mt = 0; mt < 2; ++mt) {
            int mbase = m0 + wm + mt * 16 + l4 * 4;
            #pragma unroll
            for (int i = 0; i < 4; ++i) {
                int m = mbase + i;
                int doc = m >> 5, t = m & 31;
                size_t dst = ((size_t)((doc >> 4) * 32 + t) * 96 + jc) * 64
                           + (doc & 15) * 4 + ji;
                Tp[dst] = f2bf(acc[mt][nt][i] + bv);
            }
        }
    }
}

// ---------------------------------------------------------------------------
// Sentence-level BiGRU: 8 docs/block, grid (4,2) = 8 blocks. h-only MFMAs;
// xp from spT (scaled) with register prefetch. T=32.
// ---------------------------------------------------------------------------
__global__ __launch_bounds__(512, 2) void sent_gru_kernel(
        const ushort_t* __restrict__ spT_f, const ushort_t* __restrict__ spT_b,
        const ushort_t* __restrict__ Whh_f, const ushort_t* __restrict__ Whh_b,
        const ushort_t* __restrict__ bhh_f, const ushort_t* __restrict__ bhh_b,
        const int* __restrict__ lens, ushort_t* __restrict__ out) {
    const int T = 32;
    __shared__ ushort_t h_buf[2][1024];
    __shared__ float bhh_lds[384];

    int tid = threadIdx.x;
    int d = blockIdx.y;
    int bx = blockIdx.x;
    int n0 = bx * 8;
    const ushort_t* spT = d ? spT_b : spT_f;
    const ushort_t* Whh = d ? Whh_b : Whh_f;
    const ushort_t* bhh = d ? bhh_b : bhh_f;
    int lane = tid & 63, wave = tid >> 6;
    int l15 = lane & 15, l4 = (lane >> 4) & 3;
    int s8 = l15 & 7;
    bool sv = l15 < 8;
    int jt = wave * 16;
    int j0 = jt + l4 * 4;
    int jc = j0 >> 2;

    if (tid < 384) bhh_lds[tid] = bf2f(bhh[tid]);
    if (tid < 256) { uint2 z = {0u, 0u}; *(uint2*)&h_buf[0][tid * 4] = z; }

    short8 ur[4], uz[4], un[4];
    #pragma unroll
    for (int kf = 0; kf < 4; ++kf) {
        int col = kf * 32 + l4 * 8;
        ur[kf] = *(const short8*)(Whh + (size_t)(jt + l15) * 128 + col);
        uz[kf] = *(const short8*)(Whh + (size_t)(128 + jt + l15) * 128 + col);
        un[kf] = *(const short8*)(Whh + (size_t)(256 + jt + l15) * 128 + col);
    }
    __syncthreads();

    floatx4 br  = *(floatx4*)&bhh_lds[j0];
    floatx4 bz  = *(floatx4*)&bhh_lds[128 + j0];
    floatx4 bhn = *(floatx4*)&bhh_lds[256 + j0];
    int lv = lens[n0 + s8];
    float hreg[4] = {0.f, 0.f, 0.f, 0.f};

    // spT group dblk = bx>>1; doc-within-group = (bx&1)*8 + s8
    const ushort_t* sp = spT + (size_t)((bx >> 1) * 32) * 96 * 64
                       + ((bx & 1) * 8 + s8) * 4;
    ushort4 xr_c, xz_c, xn_c, xr_n, xz_n, xn_n;
    {
        int t0 = d ? (T - 1) : 0;
        size_t rb = (size_t)t0 * 96 * 64;
        xr_c = *(const ushort4*)(sp + rb + (size_t)jc * 64);
        xz_c = *(const ushort4*)(sp + rb + (size_t)(32 + jc) * 64);
        xn_c = *(const ushort4*)(sp + rb + (size_t)(64 + jc) * 64);
    }

    for (int ti = 0; ti < T; ++ti) {
        int t = d ? (T - 1 - ti) : ti;
        int cur = ti & 1;
        bool have_next = (ti + 1) < T;
        if (have_next) {
            int tn = d ? (T - 2 - ti) : (ti + 1);
            size_t rb = (size_t)tn * 96 * 64;
            xr_n = *(const ushort4*)(sp + rb + (size_t)jc * 64);
            xz_n = *(const ushort4*)(sp + rb + (size_t)(32 + jc) * 64);
            xn_n = *(const ushort4*)(sp + rb + (size_t)(64 + jc) * 64);
        }
        floatx4 ar = br, az = bz, ahn = bhn;
        #pragma unroll
        for (int kf = 0; kf < 4; ++kf) {
            short8 hb = *(const short8*)&h_buf[cur][X8(kf * 4 + l4, s8)];
            ar  = MFMA16(ur[kf], hb, ar);
            az  = MFMA16(uz[kf], hb, az);
            ahn = MFMA16(un[kf], hb, ahn);
        }
        float xr[4] = {bf2f(xr_c.x), bf2f(xr_c.y), bf2f(xr_c.z), bf2f(xr_c.w)};
        float xz[4] = {bf2f(xz_c.x), bf2f(xz_c.y), bf2f(xz_c.z), bf2f(xz_c.w)};
        float xn[4] = {bf2f(xn_c.x), bf2f(xn_c.y), bf2f(xn_c.z), bf2f(xn_c.w)};
        bool valid = t < lv;
        float hnew[4];
        #pragma unroll
        for (int i = 0; i < 4; ++i) {
            float r  = sig2(xr[i] + ar[i]);
            float z  = sig2(xz[i] + az[i]);
            float nn = tanh2(xn[i] + r * ahn[i]);
            hnew[i] = valid ? (nn + z * (hreg[i] - nn)) : hreg[i];
            hreg[i] = hnew[i];
        }
        if (sv) {
            uint2 h2, o2;
            h2.x = packbf(hnew[0], hnew[1]);
            h2.y = packbf(hnew[2], hnew[3]);
            o2.x = valid ? h2.x : 0u;
            o2.y = valid ? h2.y : 0u;
            *(uint2*)&h_buf[cur ^ 1][X8(j0 >> 3, s8) + (j0 & 7)] = h2;
            *(uint2*)(out + ((size_t)(n0 + s8) * T + t) * 256 + d * 128 + j0) = o2;
        }
        if (have_next) { xr_c = xr_n; xz_c = xz_n; xn_c = xn_n; }
        bar_lds();
    }
}

// ---------------------------------------------------------------------------
// Word attention fused (proj W,b pre-scaled by 2·log2e).
// ---------------------------------------------------------------------------
#define SP 264
__global__ __launch_bounds__(256) void word_attn_kernel(const ushort_t* __restrict__ wout,
                                                        const ushort_t* __restrict__ W,
                                                        const ushort_t* __restrict__ bias,
                                                        const ushort_t* __restrict__ ctx,
                                                        const int* __restrict__ dmax,
                                                        ushort_t* __restrict__ sent) {
    __shared__ ushort_t tile[64 * SP];
    __shared__ float bc[256];
    __shared__ float sc_lds[64];
    __shared__ float p_lds[64];
    int tid = threadIdx.x, g = blockIdx.x;
    for (int idx = tid; idx < 2048; idx += 256) {
        int row = idx >> 5, k0 = (idx & 31) * 8;
        *(uint4*)&tile[row * SP + k0] = *(const uint4*)(wout + ((size_t)g * 64 + row) * 256 + k0);
    }
    if (tid < 128) bc[tid] = bf2f(bias[tid]);
    else bc[tid] = bf2f(ctx[tid - 128]);
    __syncthreads();
    int lane = tid & 63, wave = tid >> 6;
    int l15 = lane & 15, l4 = (lane >> 4) & 3;
    short8 a[8];
    #pragma unroll
    for (int kf = 0; kf < 8; ++kf)
        a[kf] = *(const short8*)&tile[(wave * 16 + l15) * SP + kf * 32 + l4 * 8];
    floatx4 acc[8];
    #pragma unroll
    for (int nt = 0; nt < 8; ++nt) {
        floatx4 c = {0.f, 0.f, 0.f, 0.f};
        #pragma unroll
        for (int kf = 0; kf < 8; ++kf) {
            short8 b = *(const short8*)(W + (size_t)(nt * 16 + l15) * 256 + kf * 32 + l4 * 8);
            c = MFMA16(a[kf], b, c);
        }
        acc[nt] = c;
    }
    float s[4] = {0.f, 0.f, 0.f, 0.f};
    #pragma unroll
    for (int nt = 0; nt < 8; ++nt) {
        float bv = bc[nt * 16 + l15], cv = bc[128 + nt * 16 + l15];
        #pragma unroll
        for (int i = 0; i < 4; ++i)
            s[i] += tanh2(acc[nt][i] + bv) * cv;
    }
    #pragma unroll
    for (int i = 0; i < 4; ++i) {
        s[i] += __shfl_xor(s[i], 1);
        s[i] += __shfl_xor(s[i], 2);
        s[i] += __shfl_xor(s[i], 4);
        s[i] += __shfl_xor(s[i], 8);
    }
    if (l15 == 0) {
        #pragma unroll
        for (int i = 0; i < 4; ++i) sc_lds[wave * 16 + l4 * 4 + i] = s[i];
    }
    __syncthreads();
    if (tid < 64) {
        int ml = dmax[tid & 31];
        for (int off = 32; off; off >>= 1) ml = max(ml, __shfl_xor(ml, off));
        bool v = tid < ml;
        float sc = v ? sc_lds[tid] : -1e30f;
        float mx = sc;
        for (int off = 32; off; off >>= 1) mx = fmaxf(mx, __shfl_xor(mx, off));
        float e = v ? __expf(sc - mx) : 0.f;
        float sum = e;
        for (int off = 32; off; off >>= 1) sum += __shfl_xor(sum, off);
        p_lds[tid] = e * frcp(fmaxf(sum, 1e-30f));
    }
    __syncthreads();
    float acc2 = 0.f;
    for (int t = 0; t < 64; ++t) acc2 += p_lds[t] * bf2f(tile[t * SP + tid]);
    sent[(size_t)g * 256 + tid] = f2bf(acc2);
}

// ---------------------------------------------------------------------------
// Sentence attention + FC fused (proj pre-scaled; FC unscaled).
// ---------------------------------------------------------------------------
__global__ __launch_bounds__(256) void sent_attn_fc_kernel(const ushort_t* __restrict__ sout,
                                                           const ushort_t* __restrict__ W,
                                                           const ushort_t* __restrict__ bias,
                                                           const ushort_t* __restrict__ ctx,
                                                           const ushort_t* __restrict__ fcW,
                                                           const ushort_t* __restrict__ fcb,
                                                           const int* __restrict__ slens,
                                                           const int* __restrict__ flagp,
                                                           void* __restrict__ outp) {
    __shared__ ushort_t tile[32 * SP];
    __shared__ float bc[256];
    __shared__ float sc_lds[32];
    __shared__ float p_lds[32];
    __shared__ float dv[256];
    int tid = threadIdx.x, g = blockIdx.x;
    for (int idx = tid; idx < 1024; idx += 256) {
        int row = idx >> 5, k0 = (idx & 31) * 8;
        *(uint4*)&tile[row * SP + k0] = *(const uint4*)(sout + ((size_t)g * 32 + row) * 256 + k0);
    }
    if (tid < 128) bc[tid] = bf2f(bias[tid]);
    else bc[tid] = bf2f(ctx[tid - 128]);
    __syncthreads();
    int lane = tid & 63, wave = tid >> 6;
    int l15 = lane & 15, l4 = (lane >> 4) & 3;
    if (wave < 2) {
        short8 a[8];
        #pragma unroll
        for (int kf = 0; kf < 8; ++kf)
            a[kf] = *(const short8*)&tile[(wave * 16 + l15) * SP + kf * 32 + l4 * 8];
        floatx4 acc[8];
        #pragma unroll
        for (int nt = 0; nt < 8; ++nt) {
            floatx4 c = {0.f, 0.f, 0.f, 0.f};
            #pragma unroll
            for (int kf = 0; kf < 8; ++kf) {
                short8 b = *(const short8*)(W + (size_t)(nt * 16 + l15) * 256 + kf * 32 + l4 * 8);
                c = MFMA16(a[kf], b, c);
            }
            acc[nt] = c;
        }
        float s[4] = {0.f, 0.f, 0.f, 0.f};
        #pragma unroll
        for (int nt = 0; nt < 8; ++nt) {
            float bv = bc[nt * 16 + l15], cv = bc[128 + nt * 16 + l15];
            #pragma unroll
            for (int i = 0; i < 4; ++i)
                s[i] += tanh2(acc[nt][i] + bv) * cv;
        }
        #pragma unroll
        for (int i = 0; i < 4; ++i) {
            s[i] += __shfl_xor(s[i], 1);
            s[i] += __shfl_xor(s[i], 2);
            s[i] += __shfl_xor(s[i], 4);
            s[i] += __shfl_xor(s[i], 8);
        }
        if (l15 == 0) {
            #pragma unroll
            for (int i = 0; i < 4; ++i) sc_lds[wave * 16 + l4 * 4 + i] = s[i];
        }
    }
    __syncthreads();
    if (tid < 32) {
        int ml = slens[tid];
        for (int off = 16; off; off >>= 1) ml = max(ml, __shfl_xor(ml, off, 32));
        bool v = tid < ml;
        float sc = v ? sc_lds[tid] : -1e30f;
        float mx = sc;
        for (int off = 16; off; off >>= 1) mx = fmaxf(mx, __shfl_xor(mx, off, 32));
        float e = v ? __expf(sc - mx) : 0.f;
        float sum = e;
        for (int off = 16; off; off >>= 1) sum += __shfl_xor(sum, off, 32);
        p_lds[tid] = e * frcp(fmaxf(sum, 1e-30f));
    }
    __syncthreads();
    float acc2 = 0.f;
    for (int t = 0; t < 32; ++t) acc2 += p_lds[t] * bf2f(tile[t * SP + tid]);
    dv[tid] = acc2;
    __syncthreads();
    int c = tid >> 5, q0 = (tid & 31) * 8;
    float partial = 0.f;
    #pragma unroll
    for (int q = 0; q < 8; ++q)
        partial += dv[q0 + q] * bf2f(fcW[(size_t)c * 256 + q0 + q]);
    for (int off = 16; off; off >>= 1) partial += __shfl_xor(partial, off, 32);
    if ((tid & 31) == 0) {
        float v = partial + bf2f(fcb[c]);
        if (*flagp) ((float*)outp)[g * 8 + c] = v;
        else        ((ushort_t*)outp)[g * 8 + c] = f2bf(v);
    }
}

// ---------------------------------------------------------------------------
extern "C" void kernel_launch(void* const* d_in, const int* in_sizes, int n_in,
                              void* d_out, int out_size, void* d_ws, size_t ws_size,
                              hipStream_t stream) {
    const int* x = (const int*)d_in[0];
    char* ws = (char*)d_ws;

    const size_t O_CONV = 0;            // canonical bf16 inputs (~14 MB)
    const size_t O_WOUT = 14680064;     // [65536,256] bf16  33.55 MB
    const size_t O_SENT = 48234496;     // [1024,256] bf16
    const size_t O_SOUT = 48758784;     // [1024,256] bf16
    const size_t O_SPTF = 49283072;     // spT fwd 1.5MB
    const size_t O_SPTB = 50855936;     // spT bwd
    const size_t O_LENS = 52428800;
    const size_t O_SLEN = 52432896;
    const size_t O_DMAX = 52433024;
    const size_t O_FLAG = 52433152;

    ushort_t* conv = (ushort_t*)(ws + O_CONV);
    ushort_t* wout = (ushort_t*)(ws + O_WOUT);
    ushort_t* sent = (ushort_t*)(ws + O_SENT);
    ushort_t* sout = (ushort_t*)(ws + O_SOUT);
    ushort_t* sptf = (ushort_t*)(ws + O_SPTF);
    ushort_t* sptb = (ushort_t*)(ws + O_SPTB);
    int* wlens = (int*)(ws + O_LENS);
    int* slens = (int*)(ws + O_SLEN);
    int* dmax  = (int*)(ws + O_DMAX);
    int* flag  = (int*)(ws + O_FLAG);

    static const int kMode[25]   = {0, 1,1,1,1, 1,1,1,1, 1,1,1,1, 1,1,1,1, 2,2,0, 2,2,0, 0,0};
    static const int kRowdiv[25] = {1, 128,128,1,1, 128,128,1,1, 256,128,1,1, 256,128,1,1,
                                    1,1,1, 1,1,1, 1,1};

    ConvArgs ca;
    ushort_t* cw[25];
    int off = 0, blk = 0;
    for (int i = 1; i <= 25; ++i) {
        int j = i - 1;
        int cnt = in_sizes[i];
        ca.src[j] = d_in[i];
        ca.dstoff[j] = off;
        ca.count[j] = cnt;
        ca.cumblk[j] = blk;
        ca.mode[j] = kMode[j];
        ca.rowdiv[j] = kRowdiv[j];
        cw[j] = conv + off;
        off += cnt;
        blk += (cnt + 2047) / 2048;
    }
    ca.cumblk[25] = blk;

    // 1) lengths + dtype detect
    lens_kernel<<<33, 64, 0, stream>>>(x, (const unsigned int*)d_in[1],
                                       wlens, slens, dmax, flag);
    // 2) canonicalize (+ fold activation scales into weights)
    convert_kernel<<<blk, 256, 0, stream>>>(ca, conv, flag);
    // 3) word BiGRU (8 seqs/block, 256 blocks -> all CUs)
    word_gru_kernel<<<dim3(128, 2), 512, 0, stream>>>(
        x, cw[0],
        cw[1], cw[2], cw[3], cw[4],
        cw[5], cw[6], cw[7], cw[8],
        wlens, wout);
    // 4) word attention -> sent
    word_attn_kernel<<<1024, 256, 0, stream>>>(wout, cw[17], cw[18], cw[19], dmax, sent);
    // 5) sentence xp -> spT
    spt_gemm_kernel<<<dim3(16, 12), 256, 0, stream>>>(sent, cw[9], cw[11], sptf,
                                                      cw[13], cw[15], sptb);
    // 6) sentence BiGRU (8 docs/block, 8 blocks)
    sent_gru_kernel<<<dim3(4, 2), 512, 0, stream>>>(
        sptf, sptb, cw[10], cw[14], cw[12], cw[16], slens, sout);
    // 7) sentence attention + FC -> d_out
    sent_attn_fc_kernel<<<32, 256, 0, stream>>>(sout, cw[20], cw[21], cw[22],
                                                cw[23], cw[24], slens, flag, d_out);
    (void)n_in; (void)out_size; (void)ws_size;
}